// Round 4
// baseline (400.354 us; speedup 1.0000x reference)
//
#include <hip/hip_runtime.h>
#include <hip/hip_bf16.h>
#include <math.h>
#include <stdint.h>

namespace {

constexpr int B_ = 2, S_ = 2048, D_ = 512, H_ = 8, HD_ = 64, K_ = 31,
              FF_ = 2048, G_ = 4, E_ = 2;
constexpr int N_ = B_ * S_;
constexpr int SP_ = S_ + 30;   // padded rows per batch (15 zeros each side)
constexpr float EPS_ = 1e-6f;
constexpr int PADCAP_ = 4608;  // 4096 + 4*127 rounded up to 128-tiles

typedef __bf16 bf16x8 __attribute__((ext_vector_type(8)));
typedef unsigned short u16x8 __attribute__((ext_vector_type(8)));
typedef float f32x4 __attribute__((ext_vector_type(4)));

__device__ __forceinline__ uint16_t f2bf(float f) {
  union { float f; uint32_t u; } v; v.f = f;
  uint32_t r = v.u + 0x7FFFu + ((v.u >> 16) & 1u);
  return (uint16_t)(r >> 16);
}
__device__ __forceinline__ float bf2f(uint16_t u) {
  union { uint32_t u; float f; } v; v.u = (uint32_t)u << 16;
  return v.f;
}

__device__ __forceinline__ float gelu_f(float x) {
  const float c = 0.7978845608028654f;  // sqrt(2/pi)
  return 0.5f * x * (1.0f + tanhf(c * (x + 0.044715f * x * x * x)));
}

#define GLOAD_LDS16(gsrc, ldst)                                              \
  __builtin_amdgcn_global_load_lds(                                          \
      (const __attribute__((address_space(1))) void*)(gsrc),                 \
      (__attribute__((address_space(3))) void*)(ldst), 16, 0, 0)

#define VMCNT(n) asm volatile("s_waitcnt vmcnt(" #n ")" ::: "memory")
#define MEMBAR asm volatile("" ::: "memory")
#define BARRIER __builtin_amdgcn_s_barrier()

#define SYNC_STAGE()                                   \
  do {                                                 \
    asm volatile("s_waitcnt vmcnt(0)" ::: "memory");   \
    __syncthreads();                                   \
  } while (0)

// One K=32 step: wave (wr,wc) computes 64x64 via 4x4 frags of 16x16x32.
__device__ __forceinline__ void kstep_compute(const uint16_t* As, const uint16_t* Bs,
                                              int wr, int wc, int l15, int k8,
                                              f32x4 acc[4][4]) {
  bf16x8 a[4], b[4];
#pragma unroll
  for (int m = 0; m < 4; ++m)
    a[m] = *(const bf16x8*)(As + (size_t)(wr * 64 + m * 16 + l15) * 32 + k8);
#pragma unroll
  for (int n = 0; n < 4; ++n)
    b[n] = *(const bf16x8*)(Bs + (size_t)(wc * 64 + n * 16 + l15) * 32 + k8);
#pragma unroll
  for (int m = 0; m < 4; ++m)
#pragma unroll
    for (int n = 0; n < 4; ++n)
      acc[m][n] = __builtin_amdgcn_mfma_f32_16x16x32_bf16(a[m], b[n], acc[m][n], 0, 0, 0);
}

// Double-buffered K-loop: A[128][K], B^T[128][K] staged 32-k-steps, counted vmcnt.
template <int NK>
__device__ __forceinline__ void gemm_k_dbuf(const uint16_t* Ab, int lda,
                                            const uint16_t* Bb, int ldb,
                                            int t, int wr, int wc, int l15, int k8,
                                            uint16_t (*As)[4096], uint16_t (*Bs)[4096],
                                            f32x4 acc[4][4]) {
  int srow = t >> 2, scol = (t & 3) * 8, uoff = (t & ~63) * 8;
  const uint16_t* Ar = Ab + (size_t)srow * lda + scol;
  const uint16_t* Ar2 = Ab + (size_t)(srow + 64) * lda + scol;
  const uint16_t* Br = Bb + (size_t)srow * ldb + scol;
  const uint16_t* Br2 = Bb + (size_t)(srow + 64) * ldb + scol;
  GLOAD_LDS16(Ar, As[0] + uoff);
  GLOAD_LDS16(Ar2, As[0] + 2048 + uoff);
  GLOAD_LDS16(Br, Bs[0] + uoff);
  GLOAD_LDS16(Br2, Bs[0] + 2048 + uoff);
  int cur = 0;
  for (int ki = 0; ki < NK; ++ki) {
    if (ki + 1 < NK) {
      int k0 = (ki + 1) * 32;
      GLOAD_LDS16(Ar + k0, As[cur ^ 1] + uoff);
      GLOAD_LDS16(Ar2 + k0, As[cur ^ 1] + 2048 + uoff);
      GLOAD_LDS16(Br + k0, Bs[cur ^ 1] + uoff);
      GLOAD_LDS16(Br2 + k0, Bs[cur ^ 1] + 2048 + uoff);
      VMCNT(4);
    } else {
      VMCNT(0);
    }
    BARRIER; MEMBAR;
    kstep_compute(As[cur], Bs[cur], wr, wc, l15, k8, acc);
    MEMBAR; BARRIER;
    cur ^= 1;
  }
}

// ---------------- f32 [R][C] -> bf16 transposed [C][R], batched -------------
__global__ __launch_bounds__(256) void transpose_bf16_kernel(
    const float* __restrict__ src, uint16_t* __restrict__ dst, int R, int C) {
  __shared__ float tile[32][33];
  size_t bs = (size_t)R * C;
  const float* s = src + blockIdx.z * bs;
  uint16_t* d = dst + blockIdx.z * bs;
  int c0 = blockIdx.x * 32, r0 = blockIdx.y * 32;
  int t = threadIdx.x, tc = t & 31, tr = t >> 5;
#pragma unroll
  for (int i = 0; i < 4; ++i) {
    int r = tr + i * 8;
    tile[r][tc] = s[(size_t)(r0 + r) * C + c0 + tc];
  }
  __syncthreads();
#pragma unroll
  for (int i = 0; i < 4; ++i) {
    int rr = tr + i * 8;
    d[(size_t)(c0 + rr) * R + r0 + tc] = f2bf(tile[tc][rr]);
  }
}

// ---------------- zero pad rows of Hpad + zero row N_ of x2bf ---------------
__global__ __launch_bounds__(256) void zero_pad_kernel(uint16_t* Hpad, uint16_t* x2bf) {
  int ib = blockIdx.x, t = threadIdx.x;
  uint16_t* dst;
  if (ib < 60) {
    int b = ib / 30, j = ib % 30;
    int row = b * SP_ + (j < 15 ? j : 2048 + j);
    dst = Hpad + (size_t)row * D_;
  } else {
    dst = x2bf + (size_t)N_ * D_;
  }
  dst[t] = 0;
  dst[t + 256] = 0;
}

// ---------------- LayerNorm -> bf16 (optionally into padded Hpad) -----------
__global__ __launch_bounds__(256) void ln_bf16_kernel(
    const float* __restrict__ in, uint16_t* __restrict__ out,
    const float* __restrict__ scale, const float* __restrict__ bias, int hpad) {
  int row = blockIdx.x;
  const float* xr = in + (size_t)row * D_;
  int t = threadIdx.x;
  float v0 = xr[t], v1 = xr[t + 256];
  float s = v0 + v1, sq = v0 * v0 + v1 * v1;
  for (int o = 32; o > 0; o >>= 1) {
    s += __shfl_down(s, o);
    sq += __shfl_down(sq, o);
  }
  __shared__ float sm[8];
  __shared__ float mr[2];
  int lane = t & 63, wid = t >> 6;
  if (lane == 0) { sm[wid] = s; sm[wid + 4] = sq; }
  __syncthreads();
  if (t == 0) {
    float ts = sm[0] + sm[1] + sm[2] + sm[3];
    float tq = sm[4] + sm[5] + sm[6] + sm[7];
    float m = ts / D_;
    mr[0] = m;
    mr[1] = rsqrtf(tq / D_ - m * m + EPS_);
  }
  __syncthreads();
  float m = mr[0], rs = mr[1];
  size_t drow = hpad ? ((size_t)(row >> 11) * SP_ + 15 + (row & 2047)) : (size_t)row;
  uint16_t* orow = out + drow * D_;
  orow[t] = f2bf((v0 - m) * rs * scale[t] + bias[t]);
  orow[t + 256] = f2bf((v1 - m) * rs * scale[t + 256] + bias[t + 256]);
}

// ---------------- conv: A-window shared across 8 taps, B dbuf prefetch ------
// Per block (tm,tn,ks): 128 rows x 128 cols, taps kb..kb+ntap-1.
// A window: 192 rows x 32 cols staged once per d0 (rows >135 garbage, unused).
__global__ __launch_bounds__(256) void conv_mfma_kernel(
    const uint16_t* __restrict__ Hpad, const uint16_t* __restrict__ ckT,
    uint16_t* __restrict__ Pout) {
  __shared__ __align__(16) uint16_t As[2][6144];
  __shared__ __align__(16) uint16_t Bs[2][4096];
  int tm = blockIdx.x, tn = blockIdx.y, ks = blockIdx.z;
  int t = threadIdx.x;
  int w = t >> 6, l = t & 63, l15 = l & 15, k8 = (l >> 4) * 8;
  int wr = w >> 1, wc = w & 1;
  int row0 = tm * 128, b = row0 >> 11, s0 = row0 & 2047;
  int kb = ks * 8, ntap = (ks == 3) ? 7 : 8;
  const uint16_t* Abase = Hpad + (size_t)(b * SP_ + s0 + kb) * D_;
  int srow = t >> 2, scol = (t & 3) * 8, uoff = (t & ~63) * 8;
  f32x4 acc[4][4] = {};

  auto stageA = [&](int d0, int buf) {
    GLOAD_LDS16(Abase + (size_t)srow * D_ + d0 + scol, As[buf] + uoff);
    GLOAD_LDS16(Abase + (size_t)(srow + 64) * D_ + d0 + scol, As[buf] + 2048 + uoff);
    GLOAD_LDS16(Abase + (size_t)(srow + 128) * D_ + d0 + scol, As[buf] + 4096 + uoff);
  };
  auto stageB = [&](int k, int d0, int buf) {
    const uint16_t* Bk = ckT + (size_t)k * D_ * D_ +
                         (size_t)(tn * 128 + srow) * D_ + d0 + scol;
    GLOAD_LDS16(Bk, Bs[buf] + uoff);
    GLOAD_LDS16(Bk + (size_t)64 * D_, Bs[buf] + 2048 + uoff);
  };

  stageA(0, 0);
  stageB(kb, 0, 0);
  int acur = 0, bcur = 0;
  for (int di = 0; di < 16; ++di) {
    int d0 = di * 32;
    for (int i = 0; i < ntap; ++i) {
      if (i + 1 < ntap) {
        stageB(kb + i + 1, d0, bcur ^ 1);
        VMCNT(2);
      } else if (di + 1 < 16) {
        stageA(d0 + 32, acur ^ 1);
        stageB(kb, d0 + 32, bcur ^ 1);
        VMCNT(5);
      } else {
        VMCNT(0);
      }
      BARRIER; MEMBAR;
      const uint16_t* Ac = As[acur];
      const uint16_t* Bc = Bs[bcur];
      bf16x8 a[4], bb[4];
#pragma unroll
      for (int m = 0; m < 4; ++m)
        a[m] = *(const bf16x8*)(Ac + (size_t)(i + wr * 64 + m * 16 + l15) * 32 + k8);
#pragma unroll
      for (int n = 0; n < 4; ++n)
        bb[n] = *(const bf16x8*)(Bc + (size_t)(wc * 64 + n * 16 + l15) * 32 + k8);
#pragma unroll
      for (int m = 0; m < 4; ++m)
#pragma unroll
        for (int n = 0; n < 4; ++n)
          acc[m][n] = __builtin_amdgcn_mfma_f32_16x16x32_bf16(a[m], bb[n], acc[m][n], 0, 0, 0);
      MEMBAR; BARRIER;
      bcur ^= 1;
    }
    acur ^= 1;
  }
  uint16_t* P = Pout + (size_t)ks * N_ * D_;
#pragma unroll
  for (int m = 0; m < 4; ++m) {
    int r = row0 + wr * 64 + m * 16 + (l >> 4) * 4;
#pragma unroll
    for (int n = 0; n < 4; ++n) {
      int c = tn * 128 + wc * 64 + n * 16 + l15;
#pragma unroll
      for (int j = 0; j < 4; ++j)
        P[(size_t)(r + j) * D_ + c] = f2bf(acc[m][n][j]);
    }
  }
}

// ---------------- conv epilogue: x1 = gelu(P0+P1+P2+P3 + cb) + x ------------
__global__ __launch_bounds__(256) void conv_epi_kernel(
    const uint16_t* __restrict__ P, const float* __restrict__ cb,
    const float* __restrict__ xres, float* __restrict__ x1) {
  int idx = blockIdx.x * 256 + threadIdx.x;  // 8-elem group
  const u16x8* p0 = (const u16x8*)P;
  const u16x8* p1 = (const u16x8*)(P + (size_t)N_ * D_);
  const u16x8* p2 = (const u16x8*)(P + (size_t)2 * N_ * D_);
  const u16x8* p3 = (const u16x8*)(P + (size_t)3 * N_ * D_);
  u16x8 a = p0[idx], b = p1[idx], c = p2[idx], d = p3[idx];
  int base = idx * 8, dbase = base & (D_ - 1);
  const float* bias = cb + dbase;
  const float* xr = xres + base;
  float* o = x1 + base;
#pragma unroll
  for (int j = 0; j < 8; ++j) {
    float v = bf2f(a[j]) + bf2f(b[j]) + bf2f(c[j]) + bf2f(d[j]) + bias[j];
    o[j] = gelu_f(v) + xr[j];
  }
}

// ------- fused QKV GEMM -> bf16 Q(scaled 1/8), K, V ------------------------
__global__ __launch_bounds__(256) void gemm_qkv_kernel(
    const uint16_t* __restrict__ A, const uint16_t* __restrict__ BT,
    const float* __restrict__ bq, const float* __restrict__ bk,
    const float* __restrict__ bv, uint16_t* __restrict__ Qb,
    uint16_t* __restrict__ Kb, uint16_t* __restrict__ Vb) {
  __shared__ __align__(16) uint16_t As[2][4096], Bs[2][4096];
  int tm = blockIdx.x, tn = blockIdx.y;
  int t = threadIdx.x;
  int w = t >> 6, l = t & 63, l15 = l & 15, k8 = (l >> 4) * 8;
  int wr = w >> 1, wc = w & 1;
  int row0 = tm * 128;
  f32x4 acc[4][4] = {};
  gemm_k_dbuf<16>(A + (size_t)row0 * D_, D_, BT + (size_t)(tn * 128) * D_, D_,
                  t, wr, wc, l15, k8, As, Bs, acc);
  int sel = tn >> 2, col0 = (tn & 3) * 128;
  uint16_t* dst = sel == 0 ? Qb : (sel == 1 ? Kb : Vb);
  const float* bias = sel == 0 ? bq : (sel == 1 ? bk : bv);
  float scl = sel == 0 ? 0.125f : 1.0f;
#pragma unroll
  for (int m = 0; m < 4; ++m) {
    int r = row0 + wr * 64 + m * 16 + (l >> 4) * 4;
#pragma unroll
    for (int n = 0; n < 4; ++n) {
      int c = col0 + wc * 64 + n * 16 + l15;
#pragma unroll
      for (int j = 0; j < 4; ++j)
        dst[(size_t)(r + j) * D_ + c] = f2bf((acc[m][n][j] + bias[c]) * scl);
    }
  }
}

// ---------------- WO GEMM + bias + residual -> out (f32) + x2 (bf16) --------
__global__ __launch_bounds__(256) void gemm_wo_kernel(
    const uint16_t* __restrict__ A, const uint16_t* __restrict__ BT,
    const float* __restrict__ bo, const float* __restrict__ res,
    float* __restrict__ out, uint16_t* __restrict__ x2bf) {
  __shared__ __align__(16) uint16_t As[2][4096], Bs[2][4096];
  int tm = blockIdx.x, tn = blockIdx.y;
  int t = threadIdx.x;
  int w = t >> 6, l = t & 63, l15 = l & 15, k8 = (l >> 4) * 8;
  int wr = w >> 1, wc = w & 1;
  int row0 = tm * 128;
  f32x4 acc[4][4] = {};
  gemm_k_dbuf<16>(A + (size_t)row0 * D_, D_, BT + (size_t)(tn * 128) * D_, D_,
                  t, wr, wc, l15, k8, As, Bs, acc);
#pragma unroll
  for (int m = 0; m < 4; ++m) {
    int r = row0 + wr * 64 + m * 16 + (l >> 4) * 4;
#pragma unroll
    for (int n = 0; n < 4; ++n) {
      int c = tn * 128 + wc * 64 + n * 16 + l15;
#pragma unroll
      for (int j = 0; j < 4; ++j) {
        float v = acc[m][n][j] + bo[c] + res[(size_t)(r + j) * D_ + c];
        out[(size_t)(r + j) * D_ + c] = v;
        x2bf[(size_t)(r + j) * D_ + c] = f2bf(v);
      }
    }
  }
}

// ---------------- MFMA flash attention (unchanged) --------------------------
__global__ __launch_bounds__(256) void attn_mfma_kernel(
    const uint16_t* __restrict__ Qbf, const uint16_t* __restrict__ Kbf,
    const uint16_t* __restrict__ Vbf, uint16_t* __restrict__ obf) {
  __shared__ __align__(16) uint16_t Ks[4096];   // [64 key][64 d] swizzled
  __shared__ __align__(16) uint16_t Vt[4096];   // [64 d][64 key] swizzled
  __shared__ __align__(16) uint16_t Plds[4096]; // per-wave [16 q][64 key] swizzled
  int qt = blockIdx.x, h = blockIdx.y, b = blockIdx.z;
  int t = threadIdx.x, w = t >> 6, l = t & 63;
  int l15 = l & 15, g = l >> 4;
  int qbase = b * S_ + qt * 64;
  bf16x8 qa[2];
  {
    const uint16_t* qp = Qbf + (size_t)(qbase + w * 16 + l15) * D_ + h * HD_;
#pragma unroll
    for (int ks = 0; ks < 2; ++ks)
      qa[ks] = *(const bf16x8*)(qp + ks * 32 + g * 8);
  }
  f32x4 acc_o[4] = {};
  float m_run[4], l_run[4];
#pragma unroll
  for (int j = 0; j < 4; ++j) { m_run[j] = -INFINITY; l_run[j] = 0.f; }
  char* Pw = (char*)Plds + w * 2048;

  for (int kt = 0; kt < S_ / 64; ++kt) {
    __syncthreads();
    {
      int c0 = t, c1 = t + 256;
      int r0 = c0 >> 3, sb0 = ((c0 & 7) * 16) ^ ((r0 & 7) << 4);
      int r1 = c1 >> 3, sb1 = ((c1 & 7) * 16) ^ ((r1 & 7) << 4);
      GLOAD_LDS16((const char*)(Kbf + (size_t)(b * S_ + kt * 64 + r0) * D_ + h * HD_) + sb0,
                  (char*)Ks + (t & ~63) * 16);
      GLOAD_LDS16((const char*)(Kbf + (size_t)(b * S_ + kt * 64 + r1) * D_ + h * HD_) + sb1,
                  (char*)Ks + 4096 + (t & ~63) * 16);
    }
    {
      int r = t & 63, dh = t >> 6;
      const uint16_t* vp = Vbf + (size_t)(b * S_ + kt * 64 + r) * D_ + h * HD_ + dh * 16;
      u16x8 v0 = *(const u16x8*)vp;
      u16x8 v1 = *(const u16x8*)(vp + 8);
#pragma unroll
      for (int i = 0; i < 8; ++i) {
        int d = dh * 16 + i;
        *(uint16_t*)((char*)Vt + ((d * 128 + r * 2) ^ ((d & 7) << 4))) = v0[i];
      }
#pragma unroll
      for (int i = 0; i < 8; ++i) {
        int d = dh * 16 + 8 + i;
        *(uint16_t*)((char*)Vt + ((d * 128 + r * 2) ^ ((d & 7) << 4))) = v1[i];
      }
    }
    SYNC_STAGE();
    f32x4 accs[4] = {};
#pragma unroll
    for (int ks = 0; ks < 2; ++ks) {
#pragma unroll
      for (int n = 0; n < 4; ++n) {
        int row = n * 16 + l15;
        bf16x8 kb = *(const bf16x8*)((const char*)Ks +
                        ((row * 128 + ks * 64 + g * 16) ^ ((row & 7) << 4)));
        accs[n] = __builtin_amdgcn_mfma_f32_16x16x32_bf16(qa[ks], kb, accs[n], 0, 0, 0);
      }
    }
    float corr[4];
#pragma unroll
    for (int j = 0; j < 4; ++j) {
      float m0 = fmaxf(fmaxf(accs[0][j], accs[1][j]), fmaxf(accs[2][j], accs[3][j]));
      for (int o_ = 1; o_ < 16; o_ <<= 1) m0 = fmaxf(m0, __shfl_xor(m0, o_));
      float mnew = fmaxf(m_run[j], m0);
      corr[j] = __expf(m_run[j] - mnew);
      m_run[j] = mnew;
    }
    float rsum[4] = {0.f, 0.f, 0.f, 0.f};
#pragma unroll
    for (int n = 0; n < 4; ++n) {
#pragma unroll
      for (int j = 0; j < 4; ++j) {
        float p = __expf(accs[n][j] - m_run[j]);
        rsum[j] += p;
        int row = g * 4 + j, col = n * 16 + l15;
        *(uint16_t*)(Pw + ((row * 128 + col * 2) ^ ((row & 7) << 4))) = f2bf(p);
      }
    }
#pragma unroll
    for (int j = 0; j < 4; ++j) {
      float s = rsum[j];
      for (int o_ = 1; o_ < 16; o_ <<= 1) s += __shfl_xor(s, o_);
      l_run[j] = l_run[j] * corr[j] + s;
#pragma unroll
      for (int n = 0; n < 4; ++n) acc_o[n][j] *= corr[j];
    }
#pragma unroll
    for (int ks = 0; ks < 2; ++ks) {
      bf16x8 pa = *(const bf16x8*)(Pw +
                      ((l15 * 128 + ks * 64 + g * 16) ^ ((l15 & 7) << 4)));
#pragma unroll
      for (int n = 0; n < 4; ++n) {
        int d = n * 16 + l15;
        bf16x8 vb = *(const bf16x8*)((const char*)Vt +
                        ((d * 128 + ks * 64 + g * 16) ^ ((d & 7) << 4)));
        acc_o[n] = __builtin_amdgcn_mfma_f32_16x16x32_bf16(pa, vb, acc_o[n], 0, 0, 0);
      }
    }
  }
#pragma unroll
  for (int j = 0; j < 4; ++j) {
    float inv = 1.f / l_run[j];
    uint16_t* op = obf + (size_t)(qbase + w * 16 + g * 4 + j) * D_ + h * HD_;
#pragma unroll
    for (int n = 0; n < 4; ++n)
      op[n * 16 + l15] = f2bf(acc_o[n][j] * inv);
  }
}

// ---------------- MoE bucketing: group tokens, pad to 128 -------------------
__global__ __launch_bounds__(1024) void bucket_kernel(
    const int* __restrict__ gid, int* __restrict__ list, int* __restrict__ poff) {
  __shared__ int cnt[G_], cur[G_];
  int t = threadIdx.x;
  if (t < G_) cnt[t] = 0;
  __syncthreads();
  for (int i = t; i < N_; i += 1024) atomicAdd(&cnt[gid[i]], 1);
  __syncthreads();
  if (t == 0) {
    int off = 0;
    for (int g = 0; g < G_; ++g) {
      poff[g] = off;
      cur[g] = off;
      off += (cnt[g] + 127) & ~127;
    }
    poff[G_] = off;
  }
  __syncthreads();
  for (int i = t; i < PADCAP_; i += 1024) list[i] = N_;
  __syncthreads();
  for (int i = t; i < N_; i += 1024) {
    int p = atomicAdd(&cur[gid[i]], 1);
    list[p] = i;
  }
}

// ---------------- MoE FF1 (gathered A), dbuf, experts via grid.z ------------
__global__ __launch_bounds__(256) void ff1_mfma_kernel(
    const uint16_t* __restrict__ X, const uint16_t* __restrict__ w1T,
    const float* __restrict__ b1, const int* __restrict__ list,
    const int* __restrict__ poff, uint16_t* __restrict__ hid) {
  __shared__ __align__(16) uint16_t As[2][4096], Bs[2][4096];
  int tm = blockIdx.x, tn = blockIdx.y, e = blockIdx.z;
  int slot0 = tm * 128;
  if (slot0 >= poff[G_]) return;
  int g = 0;
#pragma unroll
  for (int gg = 1; gg < G_; ++gg) g += (slot0 >= poff[gg]);
  int t = threadIdx.x;
  int w = t >> 6, l = t & 63, l15 = l & 15, k8 = (l >> 4) * 8;
  int wr = w >> 1, wc = w & 1;
  int srow = t >> 2, scol = (t & 3) * 8, uoff = (t & ~63) * 8;
  int tokA = list[slot0 + srow];
  int tokB = list[slot0 + 64 + srow];
  const uint16_t* ArA = X + (size_t)tokA * D_ + scol;
  const uint16_t* ArB = X + (size_t)tokB * D_ + scol;
  const uint16_t* Br = w1T + ((size_t)(g * E_ + e) * FF_ + tn * 128 + srow) * D_ + scol;
  f32x4 acc[4][4] = {};
  GLOAD_LDS16(ArA, As[0] + uoff);
  GLOAD_LDS16(ArB, As[0] + 2048 + uoff);
  GLOAD_LDS16(Br, Bs[0] + uoff);
  GLOAD_LDS16(Br + (size_t)64 * D_, Bs[0] + 2048 + uoff);
  int cur = 0;
  for (int ki = 0; ki < 16; ++ki) {
    if (ki + 1 < 16) {
      int k0 = (ki + 1) * 32;
      GLOAD_LDS16(ArA + k0, As[cur ^ 1] + uoff);
      GLOAD_LDS16(ArB + k0, As[cur ^ 1] + 2048 + uoff);
      GLOAD_LDS16(Br + k0, Bs[cur ^ 1] + uoff);
      GLOAD_LDS16(Br + (size_t)64 * D_ + k0, Bs[cur ^ 1] + 2048 + uoff);
      VMCNT(4);
    } else {
      VMCNT(0);
    }
    BARRIER; MEMBAR;
    kstep_compute(As[cur], Bs[cur], wr, wc, l15, k8, acc);
    MEMBAR; BARRIER;
    cur ^= 1;
  }
  const float* bias = b1 + (size_t)(g * E_ + e) * FF_;
  uint16_t* hidE = hid + (size_t)e * PADCAP_ * FF_;
#pragma unroll
  for (int m = 0; m < 4; ++m) {
    int r = slot0 + wr * 64 + m * 16 + (l >> 4) * 4;
#pragma unroll
    for (int n = 0; n < 4; ++n) {
      int c = tn * 128 + wc * 64 + n * 16 + l15;
#pragma unroll
      for (int j = 0; j < 4; ++j)
        hidE[(size_t)(r + j) * FF_ + c] = f2bf(gelu_f(acc[m][n][j] + bias[c]));
    }
  }
}

// ---------------- MoE FF2: per-expert blocks, atomic scatter-add ------------
__global__ __launch_bounds__(256) void ff2_mfma_kernel(
    const uint16_t* __restrict__ hid, const uint16_t* __restrict__ w2T,
    const float* __restrict__ b2, const int* __restrict__ list,
    const int* __restrict__ poff, float* __restrict__ out) {
  __shared__ __align__(16) uint16_t As[2][4096], Bs[2][4096];
  int tm = blockIdx.x, tn = blockIdx.y, e = blockIdx.z;
  int slot0 = tm * 128;
  if (slot0 >= poff[G_]) return;
  int g = 0;
#pragma unroll
  for (int gg = 1; gg < G_; ++gg) g += (slot0 >= poff[gg]);
  int t = threadIdx.x;
  int w = t >> 6, l = t & 63, l15 = l & 15, k8 = (l >> 4) * 8;
  int wr = w >> 1, wc = w & 1;
  f32x4 acc[4][4] = {};
  const uint16_t* Ab = hid + ((size_t)e * PADCAP_ + slot0) * FF_;
  const uint16_t* Bb = w2T + (size_t)(g * E_ + e) * D_ * FF_ + (size_t)(tn * 128) * FF_;
  gemm_k_dbuf<64>(Ab, FF_, Bb, FF_, t, wr, wc, l15, k8, As, Bs, acc);
  const float* be = b2 + (size_t)(g * E_ + e) * D_;
#pragma unroll
  for (int m = 0; m < 4; ++m) {
    int rbase = slot0 + wr * 64 + m * 16 + (l >> 4) * 4;
#pragma unroll
    for (int j = 0; j < 4; ++j) {
      int tok = list[rbase + j];
      if (tok >= N_) continue;
#pragma unroll
      for (int n = 0; n < 4; ++n) {
        int c = tn * 128 + wc * 64 + n * 16 + l15;
        atomicAdd(&out[(size_t)tok * D_ + c], 0.5f * (acc[m][n][j] + be[c]));
      }
    }
  }
}

}  // namespace

extern "C" void kernel_launch(void* const* d_in, const int* in_sizes, int n_in,
                              void* d_out, int out_size, void* d_ws, size_t ws_size,
                              hipStream_t stream) {
  const float* x = (const float*)d_in[0];
  const int* gid = (const int*)d_in[1];
  const float* ln1s = (const float*)d_in[2];
  const float* ln1b = (const float*)d_in[3];
  const float* ck = (const float*)d_in[4];
  const float* cb = (const float*)d_in[5];
  const float* ln2s = (const float*)d_in[6];
  const float* ln2b = (const float*)d_in[7];
  const float* wq = (const float*)d_in[8];
  const float* bq = (const float*)d_in[9];
  const float* wk = (const float*)d_in[10];
  const float* bk = (const float*)d_in[11];
  const float* wv = (const float*)d_in[12];
  const float* bv = (const float*)d_in[13];
  const float* wo = (const float*)d_in[14];
  const float* bo = (const float*)d_in[15];
  const float* w1 = (const float*)d_in[16];
  const float* b1 = (const float*)d_in[17];
  const float* w2 = (const float*)d_in[18];
  const float* b2 = (const float*)d_in[19];
  float* out = (float*)d_out;

  char* ws = (char*)d_ws;
  // Region A (38 MiB), time-multiplexed:
  //  conv:  P[4] bf16 partials (16 MiB)
  //  attn:  ln2bf(4) | Qbf(4) | Kbf(4) | Vbf(4) | obf(4)   [bf16]
  //  moe:   hidbf (36 MiB)
  char* A = ws;
  uint16_t* P = (uint16_t*)A;
  uint16_t* ln2bf = (uint16_t*)A;
  uint16_t* Qbf = (uint16_t*)(A + (4ull << 20));
  uint16_t* Kbf = (uint16_t*)(A + (8ull << 20));
  uint16_t* Vbf = (uint16_t*)(A + (12ull << 20));
  uint16_t* obf = (uint16_t*)(A + (16ull << 20));
  uint16_t* hidbf = (uint16_t*)A;

  float* x1 = (float*)(ws + (38ull << 20));
  uint16_t* Hpad = (uint16_t*)(ws + (46ull << 20));
  uint16_t* ckT = (uint16_t*)(ws + (51ull << 20));
  uint16_t* wqkvT = (uint16_t*)(ws + (67ull << 20));
  uint16_t* woT = (uint16_t*)(ws + (69ull << 20));
  uint16_t* w1T = (uint16_t*)(ws + (70ull << 20));
  uint16_t* w2T = (uint16_t*)(ws + (86ull << 20));
  uint16_t* x2bf = (uint16_t*)(ws + (102ull << 20));
  int* list = (int*)(ws + (107ull << 20));
  int* poff = list + PADCAP_;

  transpose_bf16_kernel<<<dim3(16, 16, 31), 256, 0, stream>>>(ck, ckT, 512, 512);
  transpose_bf16_kernel<<<dim3(16, 16, 1), 256, 0, stream>>>(wq, wqkvT, 512, 512);
  transpose_bf16_kernel<<<dim3(16, 16, 1), 256, 0, stream>>>(wk, wqkvT + 512 * 512, 512, 512);
  transpose_bf16_kernel<<<dim3(16, 16, 1), 256, 0, stream>>>(wv, wqkvT + 2 * 512 * 512, 512, 512);
  transpose_bf16_kernel<<<dim3(16, 16, 1), 256, 0, stream>>>(wo, woT, 512, 512);
  transpose_bf16_kernel<<<dim3(64, 16, 8), 256, 0, stream>>>(w1, w1T, 512, 2048);
  transpose_bf16_kernel<<<dim3(16, 64, 8), 256, 0, stream>>>(w2, w2T, 2048, 512);
  zero_pad_kernel<<<61, 256, 0, stream>>>(Hpad, x2bf);
  bucket_kernel<<<1, 1024, 0, stream>>>(gid, list, poff);

  // conv sublayer
  ln_bf16_kernel<<<N_, 256, 0, stream>>>(x, Hpad, ln1s, ln1b, 1);
  conv_mfma_kernel<<<dim3(32, 4, 4), 256, 0, stream>>>(Hpad, ckT, P);
  conv_epi_kernel<<<1024, 256, 0, stream>>>(P, cb, x, x1);

  // attention sublayer
  ln_bf16_kernel<<<N_, 256, 0, stream>>>(x1, ln2bf, ln2s, ln2b, 0);
  gemm_qkv_kernel<<<dim3(32, 12), 256, 0, stream>>>(ln2bf, wqkvT, bq, bk, bv, Qbf, Kbf, Vbf);
  attn_mfma_kernel<<<dim3(S_ / 64, H_, B_), 256, 0, stream>>>(Qbf, Kbf, Vbf, obf);
  gemm_wo_kernel<<<dim3(32, 4), 256, 0, stream>>>(obf, woT, bo, x1, out, x2bf);

  // MoE sublayer
  ff1_mfma_kernel<<<dim3(36, 16, 2), 256, 0, stream>>>(x2bf, w1T, b1, list, poff, hidbf);
  ff2_mfma_kernel<<<dim3(36, 4, 2), 256, 0, stream>>>(hidbf, w2T, b2, list, poff, out);
}

// Round 5
// 359.375 us; speedup vs baseline: 1.1140x; 1.1140x over previous
//
#include <hip/hip_runtime.h>
#include <hip/hip_bf16.h>
#include <math.h>
#include <stdint.h>

namespace {

constexpr int B_ = 2, S_ = 2048, D_ = 512, H_ = 8, HD_ = 64, K_ = 31,
              FF_ = 2048, G_ = 4, E_ = 2;
constexpr int N_ = B_ * S_;
constexpr int SP_ = S_ + 30;   // padded rows per batch (15 zeros each side)
constexpr float EPS_ = 1e-6f;
constexpr int PADCAP_ = 4608;  // 4096 + 4*127 rounded up to 128-tiles

typedef __bf16 bf16x8 __attribute__((ext_vector_type(8)));
typedef unsigned short u16x8 __attribute__((ext_vector_type(8)));
typedef unsigned short u16x4 __attribute__((ext_vector_type(4)));
typedef float f32x4 __attribute__((ext_vector_type(4)));

__device__ __forceinline__ uint16_t f2bf(float f) {
  union { float f; uint32_t u; } v; v.f = f;
  uint32_t r = v.u + 0x7FFFu + ((v.u >> 16) & 1u);
  return (uint16_t)(r >> 16);
}
__device__ __forceinline__ float bf2f(uint16_t u) {
  union { uint32_t u; float f; } v; v.u = (uint32_t)u << 16;
  return v.f;
}

__device__ __forceinline__ float gelu_f(float x) {
  const float c = 0.7978845608028654f;  // sqrt(2/pi)
  return 0.5f * x * (1.0f + tanhf(c * (x + 0.044715f * x * x * x)));
}

#define GLOAD_LDS16(gsrc, ldst)                                              \
  __builtin_amdgcn_global_load_lds(                                          \
      (const __attribute__((address_space(1))) void*)(gsrc),                 \
      (__attribute__((address_space(3))) void*)(ldst), 16, 0, 0)

#define VMCNT(n) asm volatile("s_waitcnt vmcnt(" #n ")" ::: "memory")
#define MEMBAR asm volatile("" ::: "memory")
#define BARRIER __builtin_amdgcn_s_barrier()

// One K=32 step: wave (wr,wc) computes 64x64 via 4x4 frags of 16x16x32.
__device__ __forceinline__ void kstep_compute(const uint16_t* As, const uint16_t* Bs,
                                              int wr, int wc, int l15, int k8,
                                              f32x4 acc[4][4]) {
  bf16x8 a[4], b[4];
#pragma unroll
  for (int m = 0; m < 4; ++m)
    a[m] = *(const bf16x8*)(As + (size_t)(wr * 64 + m * 16 + l15) * 32 + k8);
#pragma unroll
  for (int n = 0; n < 4; ++n)
    b[n] = *(const bf16x8*)(Bs + (size_t)(wc * 64 + n * 16 + l15) * 32 + k8);
#pragma unroll
  for (int m = 0; m < 4; ++m)
#pragma unroll
    for (int n = 0; n < 4; ++n)
      acc[m][n] = __builtin_amdgcn_mfma_f32_16x16x32_bf16(a[m], b[n], acc[m][n], 0, 0, 0);
}

// Double-buffered K-loop: A[128][K], B^T[128][K] staged 32-k-steps, counted vmcnt.
template <int NK>
__device__ __forceinline__ void gemm_k_dbuf(const uint16_t* Ab, int lda,
                                            const uint16_t* Bb, int ldb,
                                            int t, int wr, int wc, int l15, int k8,
                                            uint16_t (*As)[4096], uint16_t (*Bs)[4096],
                                            f32x4 acc[4][4]) {
  int srow = t >> 2, scol = (t & 3) * 8, uoff = (t & ~63) * 8;
  const uint16_t* Ar = Ab + (size_t)srow * lda + scol;
  const uint16_t* Ar2 = Ab + (size_t)(srow + 64) * lda + scol;
  const uint16_t* Br = Bb + (size_t)srow * ldb + scol;
  const uint16_t* Br2 = Bb + (size_t)(srow + 64) * ldb + scol;
  GLOAD_LDS16(Ar, As[0] + uoff);
  GLOAD_LDS16(Ar2, As[0] + 2048 + uoff);
  GLOAD_LDS16(Br, Bs[0] + uoff);
  GLOAD_LDS16(Br2, Bs[0] + 2048 + uoff);
  int cur = 0;
  for (int ki = 0; ki < NK; ++ki) {
    if (ki + 1 < NK) {
      int k0 = (ki + 1) * 32;
      GLOAD_LDS16(Ar + k0, As[cur ^ 1] + uoff);
      GLOAD_LDS16(Ar2 + k0, As[cur ^ 1] + 2048 + uoff);
      GLOAD_LDS16(Br + k0, Bs[cur ^ 1] + uoff);
      GLOAD_LDS16(Br2 + k0, Bs[cur ^ 1] + 2048 + uoff);
      VMCNT(4);
    } else {
      VMCNT(0);
    }
    BARRIER; MEMBAR;
    kstep_compute(As[cur], Bs[cur], wr, wc, l15, k8, acc);
    MEMBAR; BARRIER;
    cur ^= 1;
  }
}

// ---------------- fused prep: all weight transposes + zero padding ----------
// f32 [R][C] -> bf16 [C][R] via 32x32 LDS tiles; block id decodes the matrix.
__global__ __launch_bounds__(256) void prep_kernel(
    const float* __restrict__ ck, const float* __restrict__ wq,
    const float* __restrict__ wk, const float* __restrict__ wv,
    const float* __restrict__ wo, const float* __restrict__ w1,
    const float* __restrict__ w2, uint16_t* __restrict__ ckT,
    uint16_t* __restrict__ wqkvT, uint16_t* __restrict__ woT,
    uint16_t* __restrict__ w1T, uint16_t* __restrict__ w2T,
    uint16_t* __restrict__ Hpad, uint16_t* __restrict__ x2bf) {
  int bi = blockIdx.x, t = threadIdx.x;
  if (bi >= 25344) {  // zero-pad blocks
    int j4 = bi - 25344;
    uint16_t* dst;
    if (j4 < 60) {
      int b = j4 / 30, j = j4 % 30;
      int row = b * SP_ + (j < 15 ? j : 2048 + j);
      dst = Hpad + (size_t)row * D_;
    } else {
      dst = x2bf + (size_t)N_ * D_;
    }
    dst[t] = 0;
    dst[t + 256] = 0;
    return;
  }
  const float* src;
  uint16_t* dst;
  int R, C, r0, c0;
  if (bi < 7936) {
    int z = bi >> 8, tile = bi & 255;
    R = 512; C = 512;
    c0 = (tile & 15) * 32; r0 = (tile >> 4) * 32;
    src = ck + (size_t)z * 262144; dst = ckT + (size_t)z * 262144;
  } else if (bi < 8960) {
    int idx = bi - 7936, mat = idx >> 8, tile = idx & 255;
    R = 512; C = 512;
    c0 = (tile & 15) * 32; r0 = (tile >> 4) * 32;
    src = mat == 0 ? wq : (mat == 1 ? wk : (mat == 2 ? wv : wo));
    dst = mat == 3 ? woT : wqkvT + (size_t)mat * 262144;
  } else if (bi < 17152) {
    int idx = bi - 8960, z = idx >> 10, tile = idx & 1023;
    R = 512; C = 2048;
    c0 = (tile & 63) * 32; r0 = (tile >> 6) * 32;
    src = w1 + (size_t)z * 1048576; dst = w1T + (size_t)z * 1048576;
  } else {
    int idx = bi - 17152, z = idx >> 10, tile = idx & 1023;
    R = 2048; C = 512;
    c0 = (tile & 15) * 32; r0 = (tile >> 4) * 32;
    src = w2 + (size_t)z * 1048576; dst = w2T + (size_t)z * 1048576;
  }
  __shared__ float tile[32][33];
  int tc = t & 31, tr = t >> 5;
#pragma unroll
  for (int i = 0; i < 4; ++i) {
    int r = tr + i * 8;
    tile[r][tc] = src[(size_t)(r0 + r) * C + c0 + tc];
  }
  __syncthreads();
#pragma unroll
  for (int i = 0; i < 4; ++i) {
    int rr = tr + i * 8;
    dst[(size_t)(c0 + rr) * R + r0 + tc] = f2bf(tile[tc][rr]);
  }
}

// ---------------- LayerNorm -> bf16 (optionally into padded Hpad) -----------
__global__ __launch_bounds__(256) void ln_bf16_kernel(
    const float* __restrict__ in, uint16_t* __restrict__ out,
    const float* __restrict__ scale, const float* __restrict__ bias, int hpad) {
  int row = blockIdx.x;
  const float* xr = in + (size_t)row * D_;
  int t = threadIdx.x;
  float v0 = xr[t], v1 = xr[t + 256];
  float s = v0 + v1, sq = v0 * v0 + v1 * v1;
  for (int o = 32; o > 0; o >>= 1) {
    s += __shfl_down(s, o);
    sq += __shfl_down(sq, o);
  }
  __shared__ float sm[8];
  __shared__ float mr[2];
  int lane = t & 63, wid = t >> 6;
  if (lane == 0) { sm[wid] = s; sm[wid + 4] = sq; }
  __syncthreads();
  if (t == 0) {
    float ts = sm[0] + sm[1] + sm[2] + sm[3];
    float tq = sm[4] + sm[5] + sm[6] + sm[7];
    float m = ts / D_;
    mr[0] = m;
    mr[1] = rsqrtf(tq / D_ - m * m + EPS_);
  }
  __syncthreads();
  float m = mr[0], rs = mr[1];
  size_t drow = hpad ? ((size_t)(row >> 11) * SP_ + 15 + (row & 2047)) : (size_t)row;
  uint16_t* orow = out + drow * D_;
  orow[t] = f2bf((v0 - m) * rs * scale[t] + bias[t]);
  orow[t + 256] = f2bf((v1 - m) * rs * scale[t + 256] + bias[t + 256]);
}

// ---------------- conv: split-K over 8 tap-slices, A shared across taps -----
__global__ __launch_bounds__(256) void conv_mfma_kernel(
    const uint16_t* __restrict__ Hpad, const uint16_t* __restrict__ ckT,
    uint16_t* __restrict__ Pout) {
  __shared__ __align__(16) uint16_t As[2][6144];
  __shared__ __align__(16) uint16_t Bs[2][4096];
  int tm = blockIdx.x, tn = blockIdx.y, ks = blockIdx.z;
  int t = threadIdx.x;
  int w = t >> 6, l = t & 63, l15 = l & 15, k8 = (l >> 4) * 8;
  int wr = w >> 1, wc = w & 1;
  int row0 = tm * 128, b = row0 >> 11, s0 = row0 & 2047;
  int kb = ks * 4, ntap = (ks == 7) ? 3 : 4;
  const uint16_t* Abase = Hpad + (size_t)(b * SP_ + s0 + kb) * D_;
  int srow = t >> 2, scol = (t & 3) * 8, uoff = (t & ~63) * 8;
  f32x4 acc[4][4] = {};

  auto stageA = [&](int d0, int buf) {
    GLOAD_LDS16(Abase + (size_t)srow * D_ + d0 + scol, As[buf] + uoff);
    GLOAD_LDS16(Abase + (size_t)(srow + 64) * D_ + d0 + scol, As[buf] + 2048 + uoff);
    GLOAD_LDS16(Abase + (size_t)(srow + 128) * D_ + d0 + scol, As[buf] + 4096 + uoff);
  };
  auto stageB = [&](int k, int d0, int buf) {
    const uint16_t* Bk = ckT + (size_t)k * D_ * D_ +
                         (size_t)(tn * 128 + srow) * D_ + d0 + scol;
    GLOAD_LDS16(Bk, Bs[buf] + uoff);
    GLOAD_LDS16(Bk + (size_t)64 * D_, Bs[buf] + 2048 + uoff);
  };

  stageA(0, 0);
  stageB(kb, 0, 0);
  int acur = 0, bcur = 0;
  for (int di = 0; di < 16; ++di) {
    int d0 = di * 32;
    for (int i = 0; i < ntap; ++i) {
      if (i + 1 < ntap) {
        stageB(kb + i + 1, d0, bcur ^ 1);
        VMCNT(2);
      } else if (di + 1 < 16) {
        stageA(d0 + 32, acur ^ 1);
        stageB(kb, d0 + 32, bcur ^ 1);
        VMCNT(5);
      } else {
        VMCNT(0);
      }
      BARRIER; MEMBAR;
      const uint16_t* Ac = As[acur];
      const uint16_t* Bc = Bs[bcur];
      bf16x8 a[4], bb[4];
#pragma unroll
      for (int m = 0; m < 4; ++m)
        a[m] = *(const bf16x8*)(Ac + (size_t)(i + wr * 64 + m * 16 + l15) * 32 + k8);
#pragma unroll
      for (int n = 0; n < 4; ++n)
        bb[n] = *(const bf16x8*)(Bc + (size_t)(wc * 64 + n * 16 + l15) * 32 + k8);
#pragma unroll
      for (int m = 0; m < 4; ++m)
#pragma unroll
        for (int n = 0; n < 4; ++n)
          acc[m][n] = __builtin_amdgcn_mfma_f32_16x16x32_bf16(a[m], bb[n], acc[m][n], 0, 0, 0);
      MEMBAR; BARRIER;
      bcur ^= 1;
    }
    acur ^= 1;
  }
  uint16_t* P = Pout + (size_t)ks * N_ * D_;
#pragma unroll
  for (int m = 0; m < 4; ++m) {
    int r = row0 + wr * 64 + m * 16 + (l >> 4) * 4;
#pragma unroll
    for (int n = 0; n < 4; ++n) {
      int c = tn * 128 + wc * 64 + n * 16 + l15;
#pragma unroll
      for (int j = 0; j < 4; ++j)
        P[(size_t)(r + j) * D_ + c] = f2bf(acc[m][n][j]);
    }
  }
}

// ---------------- conv epilogue: x1 = gelu(sum P + cb) + x ------------------
__global__ __launch_bounds__(256) void conv_epi_kernel(
    const uint16_t* __restrict__ P, const float* __restrict__ cb,
    const float* __restrict__ xres, float* __restrict__ x1) {
  int idx = blockIdx.x * 256 + threadIdx.x;  // 8-elem group
  float vsum[8] = {};
#pragma unroll
  for (int q = 0; q < 8; ++q) {
    u16x8 pv = ((const u16x8*)(P + (size_t)q * N_ * D_))[idx];
#pragma unroll
    for (int j = 0; j < 8; ++j) vsum[j] += bf2f(pv[j]);
  }
  int base = idx * 8, dbase = base & (D_ - 1);
  const float* bias = cb + dbase;
  const float* xr = xres + base;
  float* o = x1 + base;
#pragma unroll
  for (int j = 0; j < 8; ++j)
    o[j] = gelu_f(vsum[j] + bias[j]) + xr[j];
}

// ------- fused QKV GEMM -> bf16 Q(scaled 1/8), K row-major, V^T -------------
__global__ __launch_bounds__(256) void gemm_qkv_kernel(
    const uint16_t* __restrict__ A, const uint16_t* __restrict__ BT,
    const float* __restrict__ bq, const float* __restrict__ bk,
    const float* __restrict__ bv, uint16_t* __restrict__ Qb,
    uint16_t* __restrict__ Kb, uint16_t* __restrict__ VT) {
  __shared__ __align__(16) uint16_t As[2][4096], Bs[2][4096];
  int tm = blockIdx.x, tn = blockIdx.y;
  int t = threadIdx.x;
  int w = t >> 6, l = t & 63, l15 = l & 15, g = l >> 4, k8 = g * 8;
  int wr = w >> 1, wc = w & 1;
  int row0 = tm * 128;
  f32x4 acc[4][4] = {};
  gemm_k_dbuf<16>(A + (size_t)row0 * D_, D_, BT + (size_t)(tn * 128) * D_, D_,
                  t, wr, wc, l15, k8, As, Bs, acc);
  int sel = tn >> 2, col0 = (tn & 3) * 128;
  if (sel < 2) {
    uint16_t* dst = sel == 0 ? Qb : Kb;
    const float* bias = sel == 0 ? bq : bk;
    float scl = sel == 0 ? 0.125f : 1.0f;
#pragma unroll
    for (int m = 0; m < 4; ++m) {
      int r = row0 + wr * 64 + m * 16 + g * 4;
#pragma unroll
      for (int n = 0; n < 4; ++n) {
        int c = col0 + wc * 64 + n * 16 + l15;
#pragma unroll
        for (int j = 0; j < 4; ++j)
          dst[(size_t)(r + j) * D_ + c] = f2bf((acc[m][n][j] + bias[c]) * scl);
      }
    }
  } else {
    // V: store transposed [b][h][d][s] for direct attn staging
#pragma unroll
    for (int m = 0; m < 4; ++m) {
      int tb = row0 + wr * 64 + m * 16 + g * 4;
      int b = tb >> 11, s = tb & 2047;
#pragma unroll
      for (int n = 0; n < 4; ++n) {
        int c = col0 + wc * 64 + n * 16 + l15;
        int hh = c >> 6, d = c & 63;
        u16x4 pack;
#pragma unroll
        for (int j = 0; j < 4; ++j) pack[j] = f2bf(acc[m][n][j] + bv[c]);
        *(u16x4*)(VT + ((size_t)((b * H_ + hh) * HD_ + d) * S_ + s)) = pack;
      }
    }
  }
}

// ---------------- WO GEMM + bias + residual -> out (f32) + x2 (bf16) --------
__global__ __launch_bounds__(256) void gemm_wo_kernel(
    const uint16_t* __restrict__ A, const uint16_t* __restrict__ BT,
    const float* __restrict__ bo, const float* __restrict__ res,
    float* __restrict__ out, uint16_t* __restrict__ x2bf) {
  __shared__ __align__(16) uint16_t As[2][4096], Bs[2][4096];
  int tm = blockIdx.x, tn = blockIdx.y;
  int t = threadIdx.x;
  int w = t >> 6, l = t & 63, l15 = l & 15, k8 = (l >> 4) * 8;
  int wr = w >> 1, wc = w & 1;
  int row0 = tm * 128;
  f32x4 acc[4][4] = {};
  gemm_k_dbuf<16>(A + (size_t)row0 * D_, D_, BT + (size_t)(tn * 128) * D_, D_,
                  t, wr, wc, l15, k8, As, Bs, acc);
#pragma unroll
  for (int m = 0; m < 4; ++m) {
    int r = row0 + wr * 64 + m * 16 + (l >> 4) * 4;
#pragma unroll
    for (int n = 0; n < 4; ++n) {
      int c = tn * 128 + wc * 64 + n * 16 + l15;
#pragma unroll
      for (int j = 0; j < 4; ++j) {
        float v = acc[m][n][j] + bo[c] + res[(size_t)(r + j) * D_ + c];
        out[(size_t)(r + j) * D_ + c] = v;
        x2bf[(size_t)(r + j) * D_ + c] = f2bf(v);
      }
    }
  }
}

// ---------------- MFMA flash attention, swapped-QK softmax ------------------
// Block: 64 q rows, 4 waves x 16 q; K-tiles of 64 keys, double-buffered.
// S^T = mfma(K_frag, Q_frag): lane l holds scores for q = l&15,
// k = m*16 + (l>>4)*4 + j  -> in-register row softmax, 4 shuffles/tile.
__global__ __launch_bounds__(256) void attn_mfma_kernel(
    const uint16_t* __restrict__ Qbf, const uint16_t* __restrict__ Kbf,
    const uint16_t* __restrict__ VT, uint16_t* __restrict__ obf) {
  __shared__ __align__(16) uint16_t Ks[2][4096];   // [64 key][64 d] swizzled
  __shared__ __align__(16) uint16_t Vt[2][4096];   // [64 d][64 key] swizzled
  __shared__ __align__(16) uint16_t Plds[4096];    // per-wave [16 q][64 k] swz
  int qt = blockIdx.x, h = blockIdx.y, b = blockIdx.z;
  int t = threadIdx.x, w = t >> 6, l = t & 63;
  int l15 = l & 15, g = l >> 4;
  int qbase = b * S_ + qt * 64;
  bf16x8 qb_[2];
  {
    const uint16_t* qp = Qbf + (size_t)(qbase + w * 16 + l15) * D_ + h * HD_;
#pragma unroll
    for (int ks = 0; ks < 2; ++ks)
      qb_[ks] = *(const bf16x8*)(qp + ks * 32 + g * 8);
  }
  const uint16_t* Kbase = Kbf + (size_t)(b * S_) * D_ + h * HD_;
  const uint16_t* Vbase = VT + (size_t)((b * H_ + h) * HD_) * S_;
  int r0 = t >> 3, slot = t & 7, r1 = r0 + 32;
  int sb0 = (slot * 16) ^ ((r0 & 7) << 4);
  int sb1 = (slot * 16) ^ ((r1 & 7) << 4);
  int ldst = (t & ~63) * 16;

  auto stage_kv = [&](int kt, int buf) {
    const uint16_t* Kp = Kbase + (size_t)(kt * 64) * D_;
    const uint16_t* Vp = Vbase + kt * 64;
    GLOAD_LDS16((const char*)(Kp + (size_t)r0 * D_) + sb0, (char*)Ks[buf] + ldst);
    GLOAD_LDS16((const char*)(Kp + (size_t)r1 * D_) + sb1, (char*)Ks[buf] + 4096 + ldst);
    GLOAD_LDS16((const char*)(Vp + (size_t)r0 * S_) + sb0, (char*)Vt[buf] + ldst);
    GLOAD_LDS16((const char*)(Vp + (size_t)r1 * S_) + sb1, (char*)Vt[buf] + 4096 + ldst);
  };

  f32x4 acc_o[4] = {};
  float m_run = -INFINITY, l_run = 0.f;  // state for q = l15 of this wave
  char* Pw = (char*)Plds + w * 2048;

  stage_kv(0, 0);
  int cur = 0;
  for (int kt = 0; kt < S_ / 64; ++kt) {
    if (kt + 1 < S_ / 64) {
      stage_kv(kt + 1, cur ^ 1);
      VMCNT(4);
    } else {
      VMCNT(0);
    }
    BARRIER; MEMBAR;
    const char* KsC = (const char*)Ks[cur];
    const char* VtC = (const char*)Vt[cur];
    // --- S^T = K Q^T: accs[m] rows k = m*16+g*4+j, col q = l15 ---
    f32x4 accs[4] = {};
#pragma unroll
    for (int ks = 0; ks < 2; ++ks) {
#pragma unroll
      for (int m = 0; m < 4; ++m) {
        int row = m * 16 + l15;
        bf16x8 kf = *(const bf16x8*)(KsC +
                        (row * 128 + ((ks * 64 + g * 16) ^ ((row & 7) << 4))));
        accs[m] = __builtin_amdgcn_mfma_f32_16x16x32_bf16(kf, qb_[ks], accs[m], 0, 0, 0);
      }
    }
    // --- in-register online softmax for row q = l15 ---
    float mx = accs[0][0];
#pragma unroll
    for (int m = 0; m < 4; ++m)
#pragma unroll
      for (int j = 0; j < 4; ++j) mx = fmaxf(mx, accs[m][j]);
    mx = fmaxf(mx, __shfl_xor(mx, 16));
    mx = fmaxf(mx, __shfl_xor(mx, 32));
    float mnew = fmaxf(m_run, mx);
    float corr = __expf(m_run - mnew);
    m_run = mnew;
    float sum = 0.f;
#pragma unroll
    for (int m = 0; m < 4; ++m) {
      float p0 = __expf(accs[m][0] - mnew);
      float p1 = __expf(accs[m][1] - mnew);
      float p2 = __expf(accs[m][2] - mnew);
      float p3 = __expf(accs[m][3] - mnew);
      sum += (p0 + p1) + (p2 + p3);
      uint2 pk;
      pk.x = (uint32_t)f2bf(p0) | ((uint32_t)f2bf(p1) << 16);
      pk.y = (uint32_t)f2bf(p2) | ((uint32_t)f2bf(p3) << 16);
      *(uint2*)(Pw + (l15 * 128 + ((m * 32 + g * 8) ^ ((l15 & 7) << 4)))) = pk;
    }
    sum += __shfl_xor(sum, 16);
    sum += __shfl_xor(sum, 32);
    l_run = l_run * corr + sum;
    // --- rescale O (acc_o rows q = g*4+j) ---
    float cj[4];
#pragma unroll
    for (int j = 0; j < 4; ++j) cj[j] = __shfl(corr, g * 4 + j);
#pragma unroll
    for (int n = 0; n < 4; ++n)
#pragma unroll
      for (int j = 0; j < 4; ++j) acc_o[n][j] *= cj[j];
    // --- O += P V ---
#pragma unroll
    for (int ks = 0; ks < 2; ++ks) {
      bf16x8 pa = *(const bf16x8*)(Pw +
                      (l15 * 128 + ((ks * 64 + g * 16) ^ ((l15 & 7) << 4))));
#pragma unroll
      for (int n = 0; n < 4; ++n) {
        int d = n * 16 + l15;
        bf16x8 vb = *(const bf16x8*)(VtC +
                        (d * 128 + ((ks * 64 + g * 16) ^ ((d & 7) << 4))));
        acc_o[n] = __builtin_amdgcn_mfma_f32_16x16x32_bf16(pa, vb, acc_o[n], 0, 0, 0);
      }
    }
    MEMBAR; BARRIER;
    cur ^= 1;
  }
#pragma unroll
  for (int j = 0; j < 4; ++j) {
    float lr = __shfl(l_run, g * 4 + j);
    float inv = 1.f / lr;
    uint16_t* op = obf + (size_t)(qbase + w * 16 + g * 4 + j) * D_ + h * HD_;
#pragma unroll
    for (int n = 0; n < 4; ++n)
      op[n * 16 + l15] = f2bf(acc_o[n][j] * inv);
  }
}

// ---------------- MoE bucketing: group tokens, pad to 128 -------------------
__global__ __launch_bounds__(1024) void bucket_kernel(
    const int* __restrict__ gid, int* __restrict__ list, int* __restrict__ poff) {
  __shared__ int cnt[G_], cur[G_];
  int t = threadIdx.x;
  if (t < G_) cnt[t] = 0;
  __syncthreads();
  for (int i = t; i < N_; i += 1024) atomicAdd(&cnt[gid[i]], 1);
  __syncthreads();
  if (t == 0) {
    int off = 0;
    for (int g = 0; g < G_; ++g) {
      poff[g] = off;
      cur[g] = off;
      off += (cnt[g] + 127) & ~127;
    }
    poff[G_] = off;
  }
  __syncthreads();
  for (int i = t; i < PADCAP_; i += 1024) list[i] = N_;
  __syncthreads();
  for (int i = t; i < N_; i += 1024) {
    int p = atomicAdd(&cur[gid[i]], 1);
    list[p] = i;
  }
}

// ---------------- MoE FF1 (gathered A), dbuf, experts via grid.z ------------
__global__ __launch_bounds__(256) void ff1_mfma_kernel(
    const uint16_t* __restrict__ X, const uint16_t* __restrict__ w1T,
    const float* __restrict__ b1, const int* __restrict__ list,
    const int* __restrict__ poff, uint16_t* __restrict__ hid) {
  __shared__ __align__(16) uint16_t As[2][4096], Bs[2][4096];
  int tm = blockIdx.x, tn = blockIdx.y, e = blockIdx.z;
  int slot0 = tm * 128;
  if (slot0 >= poff[G_]) return;
  int g = 0;
#pragma unroll
  for (int gg = 1; gg < G_; ++gg) g += (slot0 >= poff[gg]);
  int t = threadIdx.x;
  int w = t >> 6, l = t & 63, l15 = l & 15, k8 = (l >> 4) * 8;
  int wr = w >> 1, wc = w & 1;
  int srow = t >> 2, scol = (t & 3) * 8, uoff = (t & ~63) * 8;
  int tokA = list[slot0 + srow];
  int tokB = list[slot0 + 64 + srow];
  const uint16_t* ArA = X + (size_t)tokA * D_ + scol;
  const uint16_t* ArB = X + (size_t)tokB * D_ + scol;
  const uint16_t* Br = w1T + ((size_t)(g * E_ + e) * FF_ + tn * 128 + srow) * D_ + scol;
  f32x4 acc[4][4] = {};
  GLOAD_LDS16(ArA, As[0] + uoff);
  GLOAD_LDS16(ArB, As[0] + 2048 + uoff);
  GLOAD_LDS16(Br, Bs[0] + uoff);
  GLOAD_LDS16(Br + (size_t)64 * D_, Bs[0] + 2048 + uoff);
  int cur = 0;
  for (int ki = 0; ki < 16; ++ki) {
    if (ki + 1 < 16) {
      int k0 = (ki + 1) * 32;
      GLOAD_LDS16(ArA + k0, As[cur ^ 1] + uoff);
      GLOAD_LDS16(ArB + k0, As[cur ^ 1] + 2048 + uoff);
      GLOAD_LDS16(Br + k0, Bs[cur ^ 1] + uoff);
      GLOAD_LDS16(Br + (size_t)64 * D_ + k0, Bs[cur ^ 1] + 2048 + uoff);
      VMCNT(4);
    } else {
      VMCNT(0);
    }
    BARRIER; MEMBAR;
    kstep_compute(As[cur], Bs[cur], wr, wc, l15, k8, acc);
    MEMBAR; BARRIER;
    cur ^= 1;
  }
  const float* bias = b1 + (size_t)(g * E_ + e) * FF_;
  uint16_t* hidE = hid + (size_t)e * PADCAP_ * FF_;
#pragma unroll
  for (int m = 0; m < 4; ++m) {
    int r = slot0 + wr * 64 + m * 16 + (l >> 4) * 4;
#pragma unroll
    for (int n = 0; n < 4; ++n) {
      int c = tn * 128 + wc * 64 + n * 16 + l15;
#pragma unroll
      for (int j = 0; j < 4; ++j)
        hidE[(size_t)(r + j) * FF_ + c] = f2bf(gelu_f(acc[m][n][j] + bias[c]));
    }
  }
}

// ---------------- MoE FF2: per-expert blocks, atomic scatter-add ------------
__global__ __launch_bounds__(256) void ff2_mfma_kernel(
    const uint16_t* __restrict__ hid, const uint16_t* __restrict__ w2T,
    const float* __restrict__ b2, const int* __restrict__ list,
    const int* __restrict__ poff, float* __restrict__ out) {
  __shared__ __align__(16) uint16_t As[2][4096], Bs[2][4096];
  int tm = blockIdx.x, tn = blockIdx.y, e = blockIdx.z;
  int slot0 = tm * 128;
  if (slot0 >= poff[G_]) return;
  int g = 0;
#pragma unroll
  for (int gg = 1; gg < G_; ++gg) g += (slot0 >= poff[gg]);
  int t = threadIdx.x;
  int w = t >> 6, l = t & 63, l15 = l & 15, k8 = (l >> 4) * 8;
  int wr = w >> 1, wc = w & 1;
  f32x4 acc[4][4] = {};
  const uint16_t* Ab = hid + ((size_t)e * PADCAP_ + slot0) * FF_;
  const uint16_t* Bb = w2T + (size_t)(g * E_ + e) * D_ * FF_ + (size_t)(tn * 128) * FF_;
  gemm_k_dbuf<64>(Ab, FF_, Bb, FF_, t, wr, wc, l15, k8, As, Bs, acc);
  const float* be = b2 + (size_t)(g * E_ + e) * D_;
#pragma unroll
  for (int m = 0; m < 4; ++m) {
    int rbase = slot0 + wr * 64 + m * 16 + (l >> 4) * 4;
#pragma unroll
    for (int j = 0; j < 4; ++j) {
      int tok = list[rbase + j];
      if (tok >= N_) continue;
#pragma unroll
      for (int n = 0; n < 4; ++n) {
        int c = tn * 128 + wc * 64 + n * 16 + l15;
        atomicAdd(&out[(size_t)tok * D_ + c], 0.5f * (acc[m][n][j] + be[c]));
      }
    }
  }
}

}  // namespace

extern "C" void kernel_launch(void* const* d_in, const int* in_sizes, int n_in,
                              void* d_out, int out_size, void* d_ws, size_t ws_size,
                              hipStream_t stream) {
  const float* x = (const float*)d_in[0];
  const int* gid = (const int*)d_in[1];
  const float* ln1s = (const float*)d_in[2];
  const float* ln1b = (const float*)d_in[3];
  const float* ck = (const float*)d_in[4];
  const float* cb = (const float*)d_in[5];
  const float* ln2s = (const float*)d_in[6];
  const float* ln2b = (const float*)d_in[7];
  const float* wq = (const float*)d_in[8];
  const float* bq = (const float*)d_in[9];
  const float* wk = (const float*)d_in[10];
  const float* bk = (const float*)d_in[11];
  const float* wv = (const float*)d_in[12];
  const float* bv = (const float*)d_in[13];
  const float* wo = (const float*)d_in[14];
  const float* bo = (const float*)d_in[15];
  const float* w1 = (const float*)d_in[16];
  const float* b1 = (const float*)d_in[17];
  const float* w2 = (const float*)d_in[18];
  const float* b2 = (const float*)d_in[19];
  float* out = (float*)d_out;

  char* ws = (char*)d_ws;
  // Region A (38 MiB), time-multiplexed:
  //  conv:  P[8] bf16 partials (32 MiB)
  //  attn:  ln2bf(4) | Qbf(4) | Kbf(4) | VT(4) | obf(4)   [bf16]
  //  moe:   hidbf (36 MiB)
  char* A = ws;
  uint16_t* P = (uint16_t*)A;
  uint16_t* ln2bf = (uint16_t*)A;
  uint16_t* Qbf = (uint16_t*)(A + (4ull << 20));
  uint16_t* Kbf = (uint16_t*)(A + (8ull << 20));
  uint16_t* VT = (uint16_t*)(A + (12ull << 20));
  uint16_t* obf = (uint16_t*)(A + (16ull << 20));
  uint16_t* hidbf = (uint16_t*)A;

  float* x1 = (float*)(ws + (38ull << 20));
  uint16_t* Hpad = (uint16_t*)(ws + (46ull << 20));
  uint16_t* ckT = (uint16_t*)(ws + (51ull << 20));
  uint16_t* wqkvT = (uint16_t*)(ws + (67ull << 20));
  uint16_t* woT = (uint16_t*)(ws + (69ull << 20));
  uint16_t* w1T = (uint16_t*)(ws + (70ull << 20));
  uint16_t* w2T = (uint16_t*)(ws + (86ull << 20));
  uint16_t* x2bf = (uint16_t*)(ws + (102ull << 20));
  int* list = (int*)(ws + (107ull << 20));
  int* poff = list + PADCAP_;

  prep_kernel<<<25405, 256, 0, stream>>>(ck, wq, wk, wv, wo, w1, w2,
                                         ckT, wqkvT, woT, w1T, w2T, Hpad, x2bf);
  bucket_kernel<<<1, 1024, 0, stream>>>(gid, list, poff);

  // conv sublayer
  ln_bf16_kernel<<<N_, 256, 0, stream>>>(x, Hpad, ln1s, ln1b, 1);
  conv_mfma_kernel<<<dim3(32, 4, 8), 256, 0, stream>>>(Hpad, ckT, P);
  conv_epi_kernel<<<1024, 256, 0, stream>>>(P, cb, x, x1);

  // attention sublayer
  ln_bf16_kernel<<<N_, 256, 0, stream>>>(x1, ln2bf, ln2s, ln2b, 0);
  gemm_qkv_kernel<<<dim3(32, 12), 256, 0, stream>>>(ln2bf, wqkvT, bq, bk, bv, Qbf, Kbf, VT);
  attn_mfma_kernel<<<dim3(S_ / 64, H_, B_), 256, 0, stream>>>(Qbf, Kbf, VT, obf);
  gemm_wo_kernel<<<dim3(32, 4), 256, 0, stream>>>(obf, woT, bo, x1, out, x2bf);

  // MoE sublayer
  ff1_mfma_kernel<<<dim3(36, 16, 2), 256, 0, stream>>>(x2bf, w1T, b1, list, poff, hidbf);
  ff2_mfma_kernel<<<dim3(36, 4, 2), 256, 0, stream>>>(hidbf, w2T, b2, list, poff, out);
}

// Round 6
// 316.786 us; speedup vs baseline: 1.2638x; 1.1344x over previous
//
#include <hip/hip_runtime.h>
#include <hip/hip_bf16.h>
#include <math.h>
#include <stdint.h>

namespace {

constexpr int B_ = 2, S_ = 2048, D_ = 512, H_ = 8, HD_ = 64, K_ = 31,
              FF_ = 2048, G_ = 4, E_ = 2;
constexpr int N_ = B_ * S_;
constexpr int SP_ = S_ + 30;   // padded rows per batch (15 zeros each side)
constexpr float EPS_ = 1e-6f;
constexpr int PADCAP_ = 4608;  // 4096 + 4*127 rounded up to 128-tiles

typedef __bf16 bf16x8 __attribute__((ext_vector_type(8)));
typedef unsigned short u16x8 __attribute__((ext_vector_type(8)));
typedef unsigned short u16x4 __attribute__((ext_vector_type(4)));
typedef float f32x4 __attribute__((ext_vector_type(4)));

__device__ __forceinline__ uint16_t f2bf(float f) {
  union { float f; uint32_t u; } v; v.f = f;
  uint32_t r = v.u + 0x7FFFu + ((v.u >> 16) & 1u);
  return (uint16_t)(r >> 16);
}
__device__ __forceinline__ float bf2f(uint16_t u) {
  union { uint32_t u; float f; } v; v.u = (uint32_t)u << 16;
  return v.f;
}

__device__ __forceinline__ float gelu_f(float x) {
  const float c = 0.7978845608028654f;  // sqrt(2/pi)
  return 0.5f * x * (1.0f + tanhf(c * (x + 0.044715f * x * x * x)));
}

#define GLOAD_LDS16(gsrc, ldst)                                              \
  __builtin_amdgcn_global_load_lds(                                          \
      (const __attribute__((address_space(1))) void*)(gsrc),                 \
      (__attribute__((address_space(3))) void*)(ldst), 16, 0, 0)

#define VMCNT(n) asm volatile("s_waitcnt vmcnt(" #n ")" ::: "memory")
#define MEMBAR asm volatile("" ::: "memory")
#define BARRIER __builtin_amdgcn_s_barrier()

// ---- swizzled-tile K-step: tiles are [128 rows][64 k] bf16, 128B rows,
// chunk c (16B) of row r lives at byte r*128 + (c ^ (r&7))*16.
// Frag rows have row&7 == l15&7, so the XOR offset is lane-constant.
__device__ __forceinline__ void kstep_swz(const char* As, const char* Bs,
                                          int wr, int wc, int l15, int g,
                                          f32x4 acc[4][4]) {
#pragma unroll
  for (int ks = 0; ks < 2; ++ks) {
    int co = (((ks << 2) | g) ^ (l15 & 7)) << 4;
    bf16x8 a[4], b[4];
#pragma unroll
    for (int m = 0; m < 4; ++m)
      a[m] = *(const bf16x8*)(As + (wr * 64 + m * 16 + l15) * 128 + co);
#pragma unroll
    for (int n = 0; n < 4; ++n)
      b[n] = *(const bf16x8*)(Bs + (wc * 64 + n * 16 + l15) * 128 + co);
#pragma unroll
    for (int m = 0; m < 4; ++m)
#pragma unroll
      for (int n = 0; n < 4; ++n)
        acc[m][n] = __builtin_amdgcn_mfma_f32_16x16x32_bf16(a[m], b[n], acc[m][n], 0, 0, 0);
  }
}

// Double-buffered BK=64 K-loop, swizzled tiles, counted vmcnt(8).
template <int NK>
__device__ __forceinline__ void gemm_k_dbuf64(const uint16_t* Ab, int lda,
                                              const uint16_t* Bb, int ldb,
                                              int t, int wr, int wc, int l15, int g,
                                              uint16_t (*As)[8192], uint16_t (*Bs)[8192],
                                              f32x4 acc[4][4]) {
  int r8 = t >> 3, clog = (t & 7) ^ (r8 & 7);
  int ubase = (t & ~63) * 8;
  auto stage = [&](int k0, int buf) {
#pragma unroll
    for (int pi = 0; pi < 4; ++pi) {
      int row = pi * 32 + r8;
      GLOAD_LDS16(Ab + (size_t)row * lda + k0 + clog * 8, As[buf] + pi * 2048 + ubase);
      GLOAD_LDS16(Bb + (size_t)row * ldb + k0 + clog * 8, Bs[buf] + pi * 2048 + ubase);
    }
  };
  stage(0, 0);
  int cur = 0;
  for (int ki = 0; ki < NK; ++ki) {
    if (ki + 1 < NK) {
      stage((ki + 1) * 64, cur ^ 1);
      VMCNT(8);
    } else {
      VMCNT(0);
    }
    BARRIER; MEMBAR;
    kstep_swz((const char*)As[cur], (const char*)Bs[cur], wr, wc, l15, g, acc);
    MEMBAR; BARRIER;
    cur ^= 1;
  }
}

// ---------------- fused prep: all weight transposes + zero padding ----------
__global__ __launch_bounds__(256) void prep_kernel(
    const float* __restrict__ ck, const float* __restrict__ wq,
    const float* __restrict__ wk, const float* __restrict__ wv,
    const float* __restrict__ wo, const float* __restrict__ w1,
    const float* __restrict__ w2, uint16_t* __restrict__ ckT,
    uint16_t* __restrict__ wqkvT, uint16_t* __restrict__ woT,
    uint16_t* __restrict__ w1T, uint16_t* __restrict__ w2T,
    uint16_t* __restrict__ Hpad, uint16_t* __restrict__ x2bf) {
  int bi = blockIdx.x, t = threadIdx.x;
  if (bi >= 25344) {  // zero-pad blocks
    int j4 = bi - 25344;
    uint16_t* dst;
    if (j4 < 60) {
      int b = j4 / 30, j = j4 % 30;
      int row = b * SP_ + (j < 15 ? j : 2048 + j);
      dst = Hpad + (size_t)row * D_;
    } else {
      dst = x2bf + (size_t)N_ * D_;
    }
    dst[t] = 0;
    dst[t + 256] = 0;
    return;
  }
  const float* src;
  uint16_t* dst;
  int R, C, r0, c0;
  if (bi < 7936) {
    int z = bi >> 8, tile = bi & 255;
    R = 512; C = 512;
    c0 = (tile & 15) * 32; r0 = (tile >> 4) * 32;
    src = ck + (size_t)z * 262144; dst = ckT + (size_t)z * 262144;
  } else if (bi < 8960) {
    int idx = bi - 7936, mat = idx >> 8, tile = idx & 255;
    R = 512; C = 512;
    c0 = (tile & 15) * 32; r0 = (tile >> 4) * 32;
    src = mat == 0 ? wq : (mat == 1 ? wk : (mat == 2 ? wv : wo));
    dst = mat == 3 ? woT : wqkvT + (size_t)mat * 262144;
  } else if (bi < 17152) {
    int idx = bi - 8960, z = idx >> 10, tile = idx & 1023;
    R = 512; C = 2048;
    c0 = (tile & 63) * 32; r0 = (tile >> 6) * 32;
    src = w1 + (size_t)z * 1048576; dst = w1T + (size_t)z * 1048576;
  } else {
    int idx = bi - 17152, z = idx >> 10, tile = idx & 1023;
    R = 2048; C = 512;
    c0 = (tile & 15) * 32; r0 = (tile >> 4) * 32;
    src = w2 + (size_t)z * 1048576; dst = w2T + (size_t)z * 1048576;
  }
  __shared__ float tile[32][33];
  int tc = t & 31, tr = t >> 5;
#pragma unroll
  for (int i = 0; i < 4; ++i) {
    int r = tr + i * 8;
    tile[r][tc] = src[(size_t)(r0 + r) * C + c0 + tc];
  }
  __syncthreads();
#pragma unroll
  for (int i = 0; i < 4; ++i) {
    int rr = tr + i * 8;
    dst[(size_t)(c0 + rr) * R + r0 + tc] = f2bf(tile[tc][rr]);
  }
}

// ---------------- LayerNorm -> bf16 (optionally into padded Hpad) -----------
__global__ __launch_bounds__(256) void ln_bf16_kernel(
    const float* __restrict__ in, uint16_t* __restrict__ out,
    const float* __restrict__ scale, const float* __restrict__ bias, int hpad) {
  int row = blockIdx.x;
  const float* xr = in + (size_t)row * D_;
  int t = threadIdx.x;
  float v0 = xr[t], v1 = xr[t + 256];
  float s = v0 + v1, sq = v0 * v0 + v1 * v1;
  for (int o = 32; o > 0; o >>= 1) {
    s += __shfl_down(s, o);
    sq += __shfl_down(sq, o);
  }
  __shared__ float sm[8];
  __shared__ float mr[2];
  int lane = t & 63, wid = t >> 6;
  if (lane == 0) { sm[wid] = s; sm[wid + 4] = sq; }
  __syncthreads();
  if (t == 0) {
    float ts = sm[0] + sm[1] + sm[2] + sm[3];
    float tq = sm[4] + sm[5] + sm[6] + sm[7];
    float m = ts / D_;
    mr[0] = m;
    mr[1] = rsqrtf(tq / D_ - m * m + EPS_);
  }
  __syncthreads();
  float m = mr[0], rs = mr[1];
  size_t drow = hpad ? ((size_t)(row >> 11) * SP_ + 15 + (row & 2047)) : (size_t)row;
  uint16_t* orow = out + drow * D_;
  orow[t] = f2bf((v0 - m) * rs * scale[t] + bias[t]);
  orow[t + 256] = f2bf((v1 - m) * rs * scale[t + 256] + bias[t + 256]);
}

// ---------------- conv: split-K over 8 tap-slices, A shared across taps -----
// A window [192][64] swizzled (24KB), B [128][64] swizzled (16KB), both dbuf.
__global__ __launch_bounds__(256) void conv_mfma_kernel(
    const uint16_t* __restrict__ Hpad, const uint16_t* __restrict__ ckT,
    uint16_t* __restrict__ Pout) {
  __shared__ __align__(16) uint16_t As[2][12288];
  __shared__ __align__(16) uint16_t Bs[2][8192];
  int tm = blockIdx.x, tn = blockIdx.y, ks = blockIdx.z;
  int t = threadIdx.x;
  int w = t >> 6, l = t & 63, l15 = l & 15, g = l >> 4;
  int wr = w >> 1, wc = w & 1;
  int row0 = tm * 128, b = row0 >> 11, s0 = row0 & 2047;
  int kb = ks * 4, ntap = (ks == 7) ? 3 : 4;
  const uint16_t* Abase = Hpad + (size_t)(b * SP_ + s0 + kb) * D_;
  int r8 = t >> 3, clog = (t & 7) ^ (r8 & 7);
  int ubase = (t & ~63) * 8;
  f32x4 acc[4][4] = {};

  auto stageA = [&](int d0, int buf) {
#pragma unroll
    for (int pi = 0; pi < 6; ++pi) {
      int row = pi * 32 + r8;
      GLOAD_LDS16(Abase + (size_t)row * D_ + d0 + clog * 8,
                  As[buf] + pi * 2048 + ubase);
    }
  };
  auto stageB = [&](int k, int d0, int buf) {
    const uint16_t* Bk = ckT + (size_t)k * D_ * D_;
#pragma unroll
    for (int pi = 0; pi < 4; ++pi) {
      int row = pi * 32 + r8;
      GLOAD_LDS16(Bk + (size_t)(tn * 128 + row) * D_ + d0 + clog * 8,
                  Bs[buf] + pi * 2048 + ubase);
    }
  };

  stageA(0, 0);
  stageB(kb, 0, 0);
  int acur = 0, bcur = 0;
  for (int di = 0; di < 8; ++di) {
    int d0 = di * 64;
    for (int i = 0; i < ntap; ++i) {
      if (i + 1 < ntap) {
        stageB(kb + i + 1, d0, bcur ^ 1);
        VMCNT(4);
      } else if (di + 1 < 8) {
        stageA(d0 + 64, acur ^ 1);
        stageB(kb, d0 + 64, bcur ^ 1);
        VMCNT(10);
      } else {
        VMCNT(0);
      }
      BARRIER; MEMBAR;
      const char* Ac = (const char*)As[acur];
      const char* Bc = (const char*)Bs[bcur];
#pragma unroll
      for (int kk = 0; kk < 2; ++kk) {
        int coA = (((kk << 2) | g) ^ ((i + l15) & 7)) << 4;
        int coB = (((kk << 2) | g) ^ (l15 & 7)) << 4;
        bf16x8 a[4], bb[4];
#pragma unroll
        for (int m = 0; m < 4; ++m)
          a[m] = *(const bf16x8*)(Ac + (i + wr * 64 + m * 16 + l15) * 128 + coA);
#pragma unroll
        for (int n = 0; n < 4; ++n)
          bb[n] = *(const bf16x8*)(Bc + (wc * 64 + n * 16 + l15) * 128 + coB);
#pragma unroll
        for (int m = 0; m < 4; ++m)
#pragma unroll
          for (int n = 0; n < 4; ++n)
            acc[m][n] = __builtin_amdgcn_mfma_f32_16x16x32_bf16(a[m], bb[n], acc[m][n], 0, 0, 0);
      }
      MEMBAR; BARRIER;
      bcur ^= 1;
    }
    acur ^= 1;
  }
  uint16_t* P = Pout + (size_t)ks * N_ * D_;
#pragma unroll
  for (int m = 0; m < 4; ++m) {
    int r = row0 + wr * 64 + m * 16 + g * 4;
#pragma unroll
    for (int n = 0; n < 4; ++n) {
      int c = tn * 128 + wc * 64 + n * 16 + l15;
#pragma unroll
      for (int j = 0; j < 4; ++j)
        P[(size_t)(r + j) * D_ + c] = f2bf(acc[m][n][j]);
    }
  }
}

// ---------------- conv epilogue: x1 = gelu(sum P + cb) + x ------------------
__global__ __launch_bounds__(256) void conv_epi_kernel(
    const uint16_t* __restrict__ P, const float* __restrict__ cb,
    const float* __restrict__ xres, float* __restrict__ x1) {
  int idx = blockIdx.x * 256 + threadIdx.x;  // 8-elem group
  float vsum[8] = {};
#pragma unroll
  for (int q = 0; q < 8; ++q) {
    u16x8 pv = ((const u16x8*)(P + (size_t)q * N_ * D_))[idx];
#pragma unroll
    for (int j = 0; j < 8; ++j) vsum[j] += bf2f(pv[j]);
  }
  int base = idx * 8, dbase = base & (D_ - 1);
  const float* bias = cb + dbase;
  const float* xr = xres + base;
  float* o = x1 + base;
#pragma unroll
  for (int j = 0; j < 8; ++j)
    o[j] = gelu_f(vsum[j] + bias[j]) + xr[j];
}

// ------- fused QKV GEMM -> bf16 Q(scaled 1/8), K row-major, V^T -------------
__global__ __launch_bounds__(256) void gemm_qkv_kernel(
    const uint16_t* __restrict__ A, const uint16_t* __restrict__ BT,
    const float* __restrict__ bq, const float* __restrict__ bk,
    const float* __restrict__ bv, uint16_t* __restrict__ Qb,
    uint16_t* __restrict__ Kb, uint16_t* __restrict__ VT) {
  __shared__ __align__(16) uint16_t As[2][8192], Bs[2][8192];
  int tm = blockIdx.x, tn = blockIdx.y;
  int t = threadIdx.x;
  int w = t >> 6, l = t & 63, l15 = l & 15, g = l >> 4;
  int wr = w >> 1, wc = w & 1;
  int row0 = tm * 128;
  f32x4 acc[4][4] = {};
  gemm_k_dbuf64<8>(A + (size_t)row0 * D_, D_, BT + (size_t)(tn * 128) * D_, D_,
                   t, wr, wc, l15, g, As, Bs, acc);
  int sel = tn >> 2, col0 = (tn & 3) * 128;
  if (sel < 2) {
    uint16_t* dst = sel == 0 ? Qb : Kb;
    const float* bias = sel == 0 ? bq : bk;
    float scl = sel == 0 ? 0.125f : 1.0f;
#pragma unroll
    for (int m = 0; m < 4; ++m) {
      int r = row0 + wr * 64 + m * 16 + g * 4;
#pragma unroll
      for (int n = 0; n < 4; ++n) {
        int c = col0 + wc * 64 + n * 16 + l15;
#pragma unroll
        for (int j = 0; j < 4; ++j)
          dst[(size_t)(r + j) * D_ + c] = f2bf((acc[m][n][j] + bias[c]) * scl);
      }
    }
  } else {
    // V: store transposed [b][h][d][s] for direct attn staging
#pragma unroll
    for (int m = 0; m < 4; ++m) {
      int tb = row0 + wr * 64 + m * 16 + g * 4;
      int b = tb >> 11, s = tb & 2047;
#pragma unroll
      for (int n = 0; n < 4; ++n) {
        int c = col0 + wc * 64 + n * 16 + l15;
        int hh = c >> 6, d = c & 63;
        u16x4 pack;
#pragma unroll
        for (int j = 0; j < 4; ++j) pack[j] = f2bf(acc[m][n][j] + bv[c]);
        *(u16x4*)(VT + ((size_t)((b * H_ + hh) * HD_ + d) * S_ + s)) = pack;
      }
    }
  }
}

// ---------------- WO GEMM + bias + residual -> out (f32) + x2 (bf16) --------
__global__ __launch_bounds__(256) void gemm_wo_kernel(
    const uint16_t* __restrict__ A, const uint16_t* __restrict__ BT,
    const float* __restrict__ bo, const float* __restrict__ res,
    float* __restrict__ out, uint16_t* __restrict__ x2bf) {
  __shared__ __align__(16) uint16_t As[2][8192], Bs[2][8192];
  int tm = blockIdx.x, tn = blockIdx.y;
  int t = threadIdx.x;
  int w = t >> 6, l = t & 63, l15 = l & 15, g = l >> 4;
  int wr = w >> 1, wc = w & 1;
  int row0 = tm * 128;
  f32x4 acc[4][4] = {};
  gemm_k_dbuf64<8>(A + (size_t)row0 * D_, D_, BT + (size_t)(tn * 128) * D_, D_,
                   t, wr, wc, l15, g, As, Bs, acc);
#pragma unroll
  for (int m = 0; m < 4; ++m) {
    int r = row0 + wr * 64 + m * 16 + g * 4;
#pragma unroll
    for (int n = 0; n < 4; ++n) {
      int c = tn * 128 + wc * 64 + n * 16 + l15;
#pragma unroll
      for (int j = 0; j < 4; ++j) {
        float v = acc[m][n][j] + bo[c] + res[(size_t)(r + j) * D_ + c];
        out[(size_t)(r + j) * D_ + c] = v;
        x2bf[(size_t)(r + j) * D_ + c] = f2bf(v);
      }
    }
  }
}

// ---------------- MFMA flash attention, swapped-QK softmax ------------------
__global__ __launch_bounds__(256) void attn_mfma_kernel(
    const uint16_t* __restrict__ Qbf, const uint16_t* __restrict__ Kbf,
    const uint16_t* __restrict__ VT, uint16_t* __restrict__ obf) {
  __shared__ __align__(16) uint16_t Ks[2][4096];   // [64 key][64 d] swizzled
  __shared__ __align__(16) uint16_t Vt[2][4096];   // [64 d][64 key] swizzled
  __shared__ __align__(16) uint16_t Plds[4096];    // per-wave [16 q][64 k] swz
  int qt = blockIdx.x, h = blockIdx.y, b = blockIdx.z;
  int t = threadIdx.x, w = t >> 6, l = t & 63;
  int l15 = l & 15, g = l >> 4;
  int qbase = b * S_ + qt * 64;
  bf16x8 qb_[2];
  {
    const uint16_t* qp = Qbf + (size_t)(qbase + w * 16 + l15) * D_ + h * HD_;
#pragma unroll
    for (int ks = 0; ks < 2; ++ks)
      qb_[ks] = *(const bf16x8*)(qp + ks * 32 + g * 8);
  }
  const uint16_t* Kbase = Kbf + (size_t)(b * S_) * D_ + h * HD_;
  const uint16_t* Vbase = VT + (size_t)((b * H_ + h) * HD_) * S_;
  int r0 = t >> 3, slot = t & 7, r1 = r0 + 32;
  int sb0 = (slot * 16) ^ ((r0 & 7) << 4);
  int sb1 = (slot * 16) ^ ((r1 & 7) << 4);
  int ldst = (t & ~63) * 16;

  auto stage_kv = [&](int kt, int buf) {
    const uint16_t* Kp = Kbase + (size_t)(kt * 64) * D_;
    const uint16_t* Vp = Vbase + kt * 64;
    GLOAD_LDS16((const char*)(Kp + (size_t)r0 * D_) + sb0, (char*)Ks[buf] + ldst);
    GLOAD_LDS16((const char*)(Kp + (size_t)r1 * D_) + sb1, (char*)Ks[buf] + 4096 + ldst);
    GLOAD_LDS16((const char*)(Vp + (size_t)r0 * S_) + sb0, (char*)Vt[buf] + ldst);
    GLOAD_LDS16((const char*)(Vp + (size_t)r1 * S_) + sb1, (char*)Vt[buf] + 4096 + ldst);
  };

  f32x4 acc_o[4] = {};
  float m_run = -INFINITY, l_run = 0.f;  // state for q = l15 of this wave
  char* Pw = (char*)Plds + w * 2048;

  stage_kv(0, 0);
  int cur = 0;
  for (int kt = 0; kt < S_ / 64; ++kt) {
    if (kt + 1 < S_ / 64) {
      stage_kv(kt + 1, cur ^ 1);
      VMCNT(4);
    } else {
      VMCNT(0);
    }
    BARRIER; MEMBAR;
    const char* KsC = (const char*)Ks[cur];
    const char* VtC = (const char*)Vt[cur];
    f32x4 accs[4] = {};
#pragma unroll
    for (int ks = 0; ks < 2; ++ks) {
#pragma unroll
      for (int m = 0; m < 4; ++m) {
        int row = m * 16 + l15;
        bf16x8 kf = *(const bf16x8*)(KsC +
                        (row * 128 + ((ks * 64 + g * 16) ^ ((row & 7) << 4))));
        accs[m] = __builtin_amdgcn_mfma_f32_16x16x32_bf16(kf, qb_[ks], accs[m], 0, 0, 0);
      }
    }
    float mx = accs[0][0];
#pragma unroll
    for (int m = 0; m < 4; ++m)
#pragma unroll
      for (int j = 0; j < 4; ++j) mx = fmaxf(mx, accs[m][j]);
    mx = fmaxf(mx, __shfl_xor(mx, 16));
    mx = fmaxf(mx, __shfl_xor(mx, 32));
    float mnew = fmaxf(m_run, mx);
    float corr = __expf(m_run - mnew);
    m_run = mnew;
    float sum = 0.f;
#pragma unroll
    for (int m = 0; m < 4; ++m) {
      float p0 = __expf(accs[m][0] - mnew);
      float p1 = __expf(accs[m][1] - mnew);
      float p2 = __expf(accs[m][2] - mnew);
      float p3 = __expf(accs[m][3] - mnew);
      sum += (p0 + p1) + (p2 + p3);
      uint2 pk;
      pk.x = (uint32_t)f2bf(p0) | ((uint32_t)f2bf(p1) << 16);
      pk.y = (uint32_t)f2bf(p2) | ((uint32_t)f2bf(p3) << 16);
      *(uint2*)(Pw + (l15 * 128 + ((m * 32 + g * 8) ^ ((l15 & 7) << 4)))) = pk;
    }
    sum += __shfl_xor(sum, 16);
    sum += __shfl_xor(sum, 32);
    l_run = l_run * corr + sum;
    float cj[4];
#pragma unroll
    for (int j = 0; j < 4; ++j) cj[j] = __shfl(corr, g * 4 + j);
#pragma unroll
    for (int n = 0; n < 4; ++n)
#pragma unroll
      for (int j = 0; j < 4; ++j) acc_o[n][j] *= cj[j];
#pragma unroll
    for (int ks = 0; ks < 2; ++ks) {
      bf16x8 pa = *(const bf16x8*)(Pw +
                      (l15 * 128 + ((ks * 64 + g * 16) ^ ((l15 & 7) << 4))));
#pragma unroll
      for (int n = 0; n < 4; ++n) {
        int d = n * 16 + l15;
        bf16x8 vb = *(const bf16x8*)(VtC +
                        (d * 128 + ((ks * 64 + g * 16) ^ ((d & 7) << 4))));
        acc_o[n] = __builtin_amdgcn_mfma_f32_16x16x32_bf16(pa, vb, acc_o[n], 0, 0, 0);
      }
    }
    MEMBAR; BARRIER;
    cur ^= 1;
  }
#pragma unroll
  for (int j = 0; j < 4; ++j) {
    float lr = __shfl(l_run, g * 4 + j);
    float inv = 1.f / lr;
    uint16_t* op = obf + (size_t)(qbase + w * 16 + g * 4 + j) * D_ + h * HD_;
#pragma unroll
    for (int n = 0; n < 4; ++n)
      op[n * 16 + l15] = f2bf(acc_o[n][j] * inv);
  }
}

// ---------------- MoE bucketing: group tokens, pad to 128 -------------------
__global__ __launch_bounds__(1024) void bucket_kernel(
    const int* __restrict__ gid, int* __restrict__ list, int* __restrict__ poff) {
  __shared__ int cnt[G_], cur[G_];
  int t = threadIdx.x;
  if (t < G_) cnt[t] = 0;
  __syncthreads();
  for (int i = t; i < N_; i += 1024) atomicAdd(&cnt[gid[i]], 1);
  __syncthreads();
  if (t == 0) {
    int off = 0;
    for (int g = 0; g < G_; ++g) {
      poff[g] = off;
      cur[g] = off;
      off += (cnt[g] + 127) & ~127;
    }
    poff[G_] = off;
  }
  __syncthreads();
  for (int i = t; i < PADCAP_; i += 1024) list[i] = N_;
  __syncthreads();
  for (int i = t; i < N_; i += 1024) {
    int p = atomicAdd(&cur[gid[i]], 1);
    list[p] = i;
  }
}

// ---------------- MoE FF1 (gathered A), swizzled dbuf, experts via grid.z ---
__global__ __launch_bounds__(256) void ff1_mfma_kernel(
    const uint16_t* __restrict__ X, const uint16_t* __restrict__ w1T,
    const float* __restrict__ b1, const int* __restrict__ list,
    const int* __restrict__ poff, uint16_t* __restrict__ hid) {
  __shared__ __align__(16) uint16_t As[2][8192], Bs[2][8192];
  int tm = blockIdx.x, tn = blockIdx.y, e = blockIdx.z;
  int slot0 = tm * 128;
  if (slot0 >= poff[G_]) return;
  int g_ = 0;
#pragma unroll
  for (int gg = 1; gg < G_; ++gg) g_ += (slot0 >= poff[gg]);
  int t = threadIdx.x;
  int w = t >> 6, l = t & 63, l15 = l & 15, g = l >> 4;
  int wr = w >> 1, wc = w & 1;
  int r8 = t >> 3, clog = (t & 7) ^ (r8 & 7);
  int ubase = (t & ~63) * 8;
  int tok[4];
#pragma unroll
  for (int pi = 0; pi < 4; ++pi) tok[pi] = list[slot0 + pi * 32 + r8];
  const uint16_t* Bb = w1T + ((size_t)(g_ * E_ + e) * FF_ + tn * 128) * D_;
  f32x4 acc[4][4] = {};
  auto stage = [&](int k0, int buf) {
#pragma unroll
    for (int pi = 0; pi < 4; ++pi) {
      GLOAD_LDS16(X + (size_t)tok[pi] * D_ + k0 + clog * 8, As[buf] + pi * 2048 + ubase);
      GLOAD_LDS16(Bb + (size_t)(pi * 32 + r8) * D_ + k0 + clog * 8,
                  Bs[buf] + pi * 2048 + ubase);
    }
  };
  stage(0, 0);
  int cur = 0;
  for (int ki = 0; ki < 8; ++ki) {
    if (ki + 1 < 8) {
      stage((ki + 1) * 64, cur ^ 1);
      VMCNT(8);
    } else {
      VMCNT(0);
    }
    BARRIER; MEMBAR;
    kstep_swz((const char*)As[cur], (const char*)Bs[cur], wr, wc, l15, g, acc);
    MEMBAR; BARRIER;
    cur ^= 1;
  }
  const float* bias = b1 + (size_t)(g_ * E_ + e) * FF_;
  uint16_t* hidE = hid + (size_t)e * PADCAP_ * FF_;
#pragma unroll
  for (int m = 0; m < 4; ++m) {
    int r = slot0 + wr * 64 + m * 16 + g * 4;
#pragma unroll
    for (int n = 0; n < 4; ++n) {
      int c = tn * 128 + wc * 64 + n * 16 + l15;
#pragma unroll
      for (int j = 0; j < 4; ++j)
        hidE[(size_t)(r + j) * FF_ + c] = f2bf(gelu_f(acc[m][n][j] + bias[c]));
    }
  }
}

// ---------------- MoE FF2: per-expert blocks, atomic scatter-add ------------
__global__ __launch_bounds__(256) void ff2_mfma_kernel(
    const uint16_t* __restrict__ hid, const uint16_t* __restrict__ w2T,
    const float* __restrict__ b2, const int* __restrict__ list,
    const int* __restrict__ poff, float* __restrict__ out) {
  __shared__ __align__(16) uint16_t As[2][8192], Bs[2][8192];
  int tm = blockIdx.x, tn = blockIdx.y, e = blockIdx.z;
  int slot0 = tm * 128;
  if (slot0 >= poff[G_]) return;
  int g_ = 0;
#pragma unroll
  for (int gg = 1; gg < G_; ++gg) g_ += (slot0 >= poff[gg]);
  int t = threadIdx.x;
  int w = t >> 6, l = t & 63, l15 = l & 15, g = l >> 4;
  int wr = w >> 1, wc = w & 1;
  f32x4 acc[4][4] = {};
  const uint16_t* Ab = hid + ((size_t)e * PADCAP_ + slot0) * FF_;
  const uint16_t* Bb = w2T + (size_t)(g_ * E_ + e) * D_ * FF_ + (size_t)(tn * 128) * FF_;
  gemm_k_dbuf64<32>(Ab, FF_, Bb, FF_, t, wr, wc, l15, g, As, Bs, acc);
  const float* be = b2 + (size_t)(g_ * E_ + e) * D_;
#pragma unroll
  for (int m = 0; m < 4; ++m) {
    int rbase = slot0 + wr * 64 + m * 16 + g * 4;
#pragma unroll
    for (int j = 0; j < 4; ++j) {
      int tok = list[rbase + j];
      if (tok >= N_) continue;
#pragma unroll
      for (int n = 0; n < 4; ++n) {
        int c = tn * 128 + wc * 64 + n * 16 + l15;
        atomicAdd(&out[(size_t)tok * D_ + c], 0.5f * (acc[m][n][j] + be[c]));
      }
    }
  }
}

}  // namespace

extern "C" void kernel_launch(void* const* d_in, const int* in_sizes, int n_in,
                              void* d_out, int out_size, void* d_ws, size_t ws_size,
                              hipStream_t stream) {
  const float* x = (const float*)d_in[0];
  const int* gid = (const int*)d_in[1];
  const float* ln1s = (const float*)d_in[2];
  const float* ln1b = (const float*)d_in[3];
  const float* ck = (const float*)d_in[4];
  const float* cb = (const float*)d_in[5];
  const float* ln2s = (const float*)d_in[6];
  const float* ln2b = (const float*)d_in[7];
  const float* wq = (const float*)d_in[8];
  const float* bq = (const float*)d_in[9];
  const float* wk = (const float*)d_in[10];
  const float* bk = (const float*)d_in[11];
  const float* wv = (const float*)d_in[12];
  const float* bv = (const float*)d_in[13];
  const float* wo = (const float*)d_in[14];
  const float* bo = (const float*)d_in[15];
  const float* w1 = (const float*)d_in[16];
  const float* b1 = (const float*)d_in[17];
  const float* w2 = (const float*)d_in[18];
  const float* b2 = (const float*)d_in[19];
  float* out = (float*)d_out;

  char* ws = (char*)d_ws;
  // Region A (38 MiB), time-multiplexed:
  //  conv:  P[8] bf16 partials (32 MiB)
  //  attn:  ln2bf(4) | Qbf(4) | Kbf(4) | VT(4) | obf(4)   [bf16]
  //  moe:   hidbf (36 MiB)
  char* A = ws;
  uint16_t* P = (uint16_t*)A;
  uint16_t* ln2bf = (uint16_t*)A;
  uint16_t* Qbf = (uint16_t*)(A + (4ull << 20));
  uint16_t* Kbf = (uint16_t*)(A + (8ull << 20));
  uint16_t* VT = (uint16_t*)(A + (12ull << 20));
  uint16_t* obf = (uint16_t*)(A + (16ull << 20));
  uint16_t* hidbf = (uint16_t*)A;

  float* x1 = (float*)(ws + (38ull << 20));
  uint16_t* Hpad = (uint16_t*)(ws + (46ull << 20));
  uint16_t* ckT = (uint16_t*)(ws + (51ull << 20));
  uint16_t* wqkvT = (uint16_t*)(ws + (67ull << 20));
  uint16_t* woT = (uint16_t*)(ws + (69ull << 20));
  uint16_t* w1T = (uint16_t*)(ws + (70ull << 20));
  uint16_t* w2T = (uint16_t*)(ws + (86ull << 20));
  uint16_t* x2bf = (uint16_t*)(ws + (102ull << 20));
  int* list = (int*)(ws + (107ull << 20));
  int* poff = list + PADCAP_;

  prep_kernel<<<25405, 256, 0, stream>>>(ck, wq, wk, wv, wo, w1, w2,
                                         ckT, wqkvT, woT, w1T, w2T, Hpad, x2bf);
  bucket_kernel<<<1, 1024, 0, stream>>>(gid, list, poff);

  // conv sublayer
  ln_bf16_kernel<<<N_, 256, 0, stream>>>(x, Hpad, ln1s, ln1b, 1);
  conv_mfma_kernel<<<dim3(32, 4, 8), 256, 0, stream>>>(Hpad, ckT, P);
  conv_epi_kernel<<<1024, 256, 0, stream>>>(P, cb, x, x1);

  // attention sublayer
  ln_bf16_kernel<<<N_, 256, 0, stream>>>(x1, ln2bf, ln2s, ln2b, 0);
  gemm_qkv_kernel<<<dim3(32, 12), 256, 0, stream>>>(ln2bf, wqkvT, bq, bk, bv, Qbf, Kbf, VT);
  attn_mfma_kernel<<<dim3(S_ / 64, H_, B_), 256, 0, stream>>>(Qbf, Kbf, VT, obf);
  gemm_wo_kernel<<<dim3(32, 4), 256, 0, stream>>>(obf, woT, bo, x1, out, x2bf);

  // MoE sublayer
  ff1_mfma_kernel<<<dim3(36, 16, 2), 256, 0, stream>>>(x2bf, w1T, b1, list, poff, hidbf);
  ff2_mfma_kernel<<<dim3(36, 4, 2), 256, 0, stream>>>(hidbf, w2T, b2, list, poff, out);
}

// Round 7
// 313.888 us; speedup vs baseline: 1.2755x; 1.0092x over previous
//
#include <hip/hip_runtime.h>
#include <hip/hip_bf16.h>
#include <math.h>
#include <stdint.h>

namespace {

constexpr int B_ = 2, S_ = 2048, D_ = 512, H_ = 8, HD_ = 64, K_ = 31,
              FF_ = 2048, G_ = 4, E_ = 2;
constexpr int N_ = B_ * S_;
constexpr int SP_ = S_ + 30;   // padded rows per batch (15 zeros each side)
constexpr float EPS_ = 1e-6f;
constexpr int PADCAP_ = 4608;  // 4096 + 4*127 rounded up to 128-tiles

typedef __bf16 bf16x8 __attribute__((ext_vector_type(8)));
typedef unsigned short u16x8 __attribute__((ext_vector_type(8)));
typedef unsigned short u16x4 __attribute__((ext_vector_type(4)));
typedef float f32x4 __attribute__((ext_vector_type(4)));

__device__ __forceinline__ uint16_t f2bf(float f) {
  union { float f; uint32_t u; } v; v.f = f;
  uint32_t r = v.u + 0x7FFFu + ((v.u >> 16) & 1u);
  return (uint16_t)(r >> 16);
}
__device__ __forceinline__ float bf2f(uint16_t u) {
  union { uint32_t u; float f; } v; v.u = (uint32_t)u << 16;
  return v.f;
}

__device__ __forceinline__ float gelu_f(float x) {
  const float c = 0.7978845608028654f;  // sqrt(2/pi)
  return 0.5f * x * (1.0f + tanhf(c * (x + 0.044715f * x * x * x)));
}

#define GLOAD_LDS16(gsrc, ldst)                                              \
  __builtin_amdgcn_global_load_lds(                                          \
      (const __attribute__((address_space(1))) void*)(gsrc),                 \
      (__attribute__((address_space(3))) void*)(ldst), 16, 0, 0)

#define VMCNT(n) asm volatile("s_waitcnt vmcnt(" #n ")" ::: "memory")
#define MEMBAR asm volatile("" ::: "memory")
#define BARRIER __builtin_amdgcn_s_barrier()

// ---- swizzled-tile K-step: tiles are [rows][64 k] bf16, 128B rows,
// chunk c (16B) of row r lives at byte r*128 + (c ^ (r&7))*16.
__device__ __forceinline__ void kstep_swz(const char* As, const char* Bs,
                                          int wr, int wc, int l15, int g,
                                          f32x4 acc[4][4]) {
#pragma unroll
  for (int ks = 0; ks < 2; ++ks) {
    int co = (((ks << 2) | g) ^ (l15 & 7)) << 4;
    bf16x8 a[4], b[4];
#pragma unroll
    for (int m = 0; m < 4; ++m)
      a[m] = *(const bf16x8*)(As + (wr * 64 + m * 16 + l15) * 128 + co);
#pragma unroll
    for (int n = 0; n < 4; ++n)
      b[n] = *(const bf16x8*)(Bs + (wc * 64 + n * 16 + l15) * 128 + co);
#pragma unroll
    for (int m = 0; m < 4; ++m)
#pragma unroll
      for (int n = 0; n < 4; ++n)
        acc[m][n] = __builtin_amdgcn_mfma_f32_16x16x32_bf16(a[m], b[n], acc[m][n], 0, 0, 0);
  }
}

// Double-buffered BK=64 K-loop, swizzled tiles, counted vmcnt(8).
template <int NK>
__device__ __forceinline__ void gemm_k_dbuf64(const uint16_t* Ab, int lda,
                                              const uint16_t* Bb, int ldb,
                                              int t, int wr, int wc, int l15, int g,
                                              uint16_t (*As)[8192], uint16_t (*Bs)[8192],
                                              f32x4 acc[4][4]) {
  int r8 = t >> 3, clog = (t & 7) ^ (r8 & 7);
  int ubase = (t & ~63) * 8;
  auto stage = [&](int k0, int buf) {
#pragma unroll
    for (int pi = 0; pi < 4; ++pi) {
      int row = pi * 32 + r8;
      GLOAD_LDS16(Ab + (size_t)row * lda + k0 + clog * 8, As[buf] + pi * 2048 + ubase);
      GLOAD_LDS16(Bb + (size_t)row * ldb + k0 + clog * 8, Bs[buf] + pi * 2048 + ubase);
    }
  };
  stage(0, 0);
  int cur = 0;
  for (int ki = 0; ki < NK; ++ki) {
    if (ki + 1 < NK) {
      stage((ki + 1) * 64, cur ^ 1);
      VMCNT(8);
    } else {
      VMCNT(0);
    }
    BARRIER; MEMBAR;
    kstep_swz((const char*)As[cur], (const char*)Bs[cur], wr, wc, l15, g, acc);
    MEMBAR; BARRIER;
    cur ^= 1;
  }
}

// ---------------- fused prep: all weight transposes + zero padding ----------
__global__ __launch_bounds__(256) void prep_kernel(
    const float* __restrict__ ck, const float* __restrict__ wq,
    const float* __restrict__ wk, const float* __restrict__ wv,
    const float* __restrict__ wo, const float* __restrict__ w1,
    const float* __restrict__ w2, uint16_t* __restrict__ ckT,
    uint16_t* __restrict__ wqkvT, uint16_t* __restrict__ woT,
    uint16_t* __restrict__ w1T, uint16_t* __restrict__ w2T,
    uint16_t* __restrict__ Hpad, uint16_t* __restrict__ x2bf) {
  int bi = blockIdx.x, t = threadIdx.x;
  if (bi >= 25344) {  // zero-pad blocks
    int j4 = bi - 25344;
    uint16_t* dst;
    if (j4 < 60) {
      int b = j4 / 30, j = j4 % 30;
      int row = b * SP_ + (j < 15 ? j : 2048 + j);
      dst = Hpad + (size_t)row * D_;
    } else {
      dst = x2bf + (size_t)N_ * D_;
    }
    dst[t] = 0;
    dst[t + 256] = 0;
    return;
  }
  const float* src;
  uint16_t* dst;
  int R, C, r0, c0;
  if (bi < 7936) {
    int z = bi >> 8, tile = bi & 255;
    R = 512; C = 512;
    c0 = (tile & 15) * 32; r0 = (tile >> 4) * 32;
    src = ck + (size_t)z * 262144; dst = ckT + (size_t)z * 262144;
  } else if (bi < 8960) {
    int idx = bi - 7936, mat = idx >> 8, tile = idx & 255;
    R = 512; C = 512;
    c0 = (tile & 15) * 32; r0 = (tile >> 4) * 32;
    src = mat == 0 ? wq : (mat == 1 ? wk : (mat == 2 ? wv : wo));
    dst = mat == 3 ? woT : wqkvT + (size_t)mat * 262144;
  } else if (bi < 17152) {
    int idx = bi - 8960, z = idx >> 10, tile = idx & 1023;
    R = 512; C = 2048;
    c0 = (tile & 63) * 32; r0 = (tile >> 6) * 32;
    src = w1 + (size_t)z * 1048576; dst = w1T + (size_t)z * 1048576;
  } else {
    int idx = bi - 17152, z = idx >> 10, tile = idx & 1023;
    R = 2048; C = 512;
    c0 = (tile & 15) * 32; r0 = (tile >> 4) * 32;
    src = w2 + (size_t)z * 1048576; dst = w2T + (size_t)z * 1048576;
  }
  __shared__ float tile[32][33];
  int tc = t & 31, tr = t >> 5;
#pragma unroll
  for (int i = 0; i < 4; ++i) {
    int r = tr + i * 8;
    tile[r][tc] = src[(size_t)(r0 + r) * C + c0 + tc];
  }
  __syncthreads();
#pragma unroll
  for (int i = 0; i < 4; ++i) {
    int rr = tr + i * 8;
    dst[(size_t)(c0 + rr) * R + r0 + tc] = f2bf(tile[tc][rr]);
  }
}

// ---------------- LayerNorm -> bf16 (optionally into padded Hpad) -----------
__global__ __launch_bounds__(256) void ln_bf16_kernel(
    const float* __restrict__ in, uint16_t* __restrict__ out,
    const float* __restrict__ scale, const float* __restrict__ bias, int hpad) {
  int row = blockIdx.x;
  const float* xr = in + (size_t)row * D_;
  int t = threadIdx.x;
  float v0 = xr[t], v1 = xr[t + 256];
  float s = v0 + v1, sq = v0 * v0 + v1 * v1;
  for (int o = 32; o > 0; o >>= 1) {
    s += __shfl_down(s, o);
    sq += __shfl_down(sq, o);
  }
  __shared__ float sm[8];
  __shared__ float mr[2];
  int lane = t & 63, wid = t >> 6;
  if (lane == 0) { sm[wid] = s; sm[wid + 4] = sq; }
  __syncthreads();
  if (t == 0) {
    float ts = sm[0] + sm[1] + sm[2] + sm[3];
    float tq = sm[4] + sm[5] + sm[6] + sm[7];
    float m = ts / D_;
    mr[0] = m;
    mr[1] = rsqrtf(tq / D_ - m * m + EPS_);
  }
  __syncthreads();
  float m = mr[0], rs = mr[1];
  size_t drow = hpad ? ((size_t)(row >> 11) * SP_ + 15 + (row & 2047)) : (size_t)row;
  uint16_t* orow = out + drow * D_;
  orow[t] = f2bf((v0 - m) * rs * scale[t] + bias[t]);
  orow[t + 256] = f2bf((v1 - m) * rs * scale[t + 256] + bias[t + 256]);
}

// ---------------- conv: 256x256 block, 8 waves (2x4), wave tile 128x64 ------
// grid 256 blocks, 1-D; ks = bid&7 -> same-XCD blocks share one tap-slice of B.
// A window [320][64] (rows 0..258 used), B [256][64] per tap; both dbuf + swz.
__global__ __launch_bounds__(512) void conv_mfma_kernel(
    const uint16_t* __restrict__ Hpad, const uint16_t* __restrict__ ckT,
    uint16_t* __restrict__ Pout) {
  __shared__ __align__(16) uint16_t As[2][20480];
  __shared__ __align__(16) uint16_t Bs[2][16384];
  int bid = blockIdx.x;
  int ks = bid & 7, tmn = bid >> 3, tm = tmn & 15, tn = tmn >> 4;
  int t = threadIdx.x;
  int w = t >> 6, l = t & 63, l15 = l & 15, g = l >> 4;
  int wr = w >> 2, wc = w & 3;
  int row0 = tm * 256, b = row0 >> 11, s0 = row0 & 2047;
  int kb = ks * 4, ntap = (ks == 7) ? 3 : 4;
  const uint16_t* Abase = Hpad + (size_t)(b * SP_ + s0 + kb) * D_;
  int r8 = t >> 3, clog = (t & 7) ^ (r8 & 7);
  int ubase = (t & ~63) * 8;
  f32x4 acc[8][4] = {};

  auto stageA = [&](int d0, int buf) {
#pragma unroll
    for (int pi = 0; pi < 5; ++pi)
      GLOAD_LDS16(Abase + (size_t)(pi * 64 + r8) * D_ + d0 + clog * 8,
                  As[buf] + pi * 4096 + ubase);
  };
  auto stageB = [&](int k, int d0, int buf) {
    const uint16_t* Bk = ckT + (size_t)k * D_ * D_ + (size_t)(tn * 256) * D_;
#pragma unroll
    for (int pi = 0; pi < 4; ++pi)
      GLOAD_LDS16(Bk + (size_t)(pi * 64 + r8) * D_ + d0 + clog * 8,
                  Bs[buf] + pi * 4096 + ubase);
  };

  stageA(0, 0);
  stageB(kb, 0, 0);
  int acur = 0, bcur = 0;
  for (int di = 0; di < 8; ++di) {
    int d0 = di * 64;
    for (int i = 0; i < ntap; ++i) {
      if (i + 1 < ntap) {
        stageB(kb + i + 1, d0, bcur ^ 1);
        VMCNT(4);
      } else if (di + 1 < 8) {
        stageA(d0 + 64, acur ^ 1);
        stageB(kb, d0 + 64, bcur ^ 1);
        VMCNT(9);
      } else {
        VMCNT(0);
      }
      BARRIER; MEMBAR;
      const char* Ac = (const char*)As[acur];
      const char* Bc = (const char*)Bs[bcur];
#pragma unroll
      for (int kk = 0; kk < 2; ++kk) {
        int cA = (((kk << 2) | g) ^ ((i + l15) & 7)) << 4;
        int cB = (((kk << 2) | g) ^ (l15 & 7)) << 4;
        bf16x8 a[8], bb[4];
#pragma unroll
        for (int m = 0; m < 8; ++m)
          a[m] = *(const bf16x8*)(Ac + (i + wr * 128 + m * 16 + l15) * 128 + cA);
#pragma unroll
        for (int n = 0; n < 4; ++n)
          bb[n] = *(const bf16x8*)(Bc + (wc * 64 + n * 16 + l15) * 128 + cB);
#pragma unroll
        for (int m = 0; m < 8; ++m)
#pragma unroll
          for (int n = 0; n < 4; ++n)
            acc[m][n] = __builtin_amdgcn_mfma_f32_16x16x32_bf16(a[m], bb[n], acc[m][n], 0, 0, 0);
      }
      MEMBAR; BARRIER;
      bcur ^= 1;
    }
    acur ^= 1;
  }
  uint16_t* P = Pout + (size_t)ks * N_ * D_;
#pragma unroll
  for (int m = 0; m < 8; ++m) {
    int r = row0 + wr * 128 + m * 16 + g * 4;
#pragma unroll
    for (int n = 0; n < 4; ++n) {
      int c = tn * 256 + wc * 64 + n * 16 + l15;
#pragma unroll
      for (int j = 0; j < 4; ++j)
        P[(size_t)(r + j) * D_ + c] = f2bf(acc[m][n][j]);
    }
  }
}

// ---------------- conv epilogue: x1 = gelu(sum P + cb) + x ------------------
__global__ __launch_bounds__(256) void conv_epi_kernel(
    const uint16_t* __restrict__ P, const float* __restrict__ cb,
    const float* __restrict__ xres, float* __restrict__ x1) {
  int idx = blockIdx.x * 256 + threadIdx.x;  // 8-elem group
  float vsum[8] = {};
#pragma unroll
  for (int q = 0; q < 8; ++q) {
    u16x8 pv = ((const u16x8*)(P + (size_t)q * N_ * D_))[idx];
#pragma unroll
    for (int j = 0; j < 8; ++j) vsum[j] += bf2f(pv[j]);
  }
  int base = idx * 8, dbase = base & (D_ - 1);
  const float* bias = cb + dbase;
  const float* xr = xres + base;
  float* o = x1 + base;
#pragma unroll
  for (int j = 0; j < 8; ++j)
    o[j] = gelu_f(vsum[j] + bias[j]) + xr[j];
}

// ------- fused QKV GEMM -> bf16 Q(scaled 1/8), K row-major, V^T -------------
__global__ __launch_bounds__(256) void gemm_qkv_kernel(
    const uint16_t* __restrict__ A, const uint16_t* __restrict__ BT,
    const float* __restrict__ bq, const float* __restrict__ bk,
    const float* __restrict__ bv, uint16_t* __restrict__ Qb,
    uint16_t* __restrict__ Kb, uint16_t* __restrict__ VT) {
  __shared__ __align__(16) uint16_t As[2][8192], Bs[2][8192];
  int tm = blockIdx.x, tn = blockIdx.y;
  int t = threadIdx.x;
  int w = t >> 6, l = t & 63, l15 = l & 15, g = l >> 4;
  int wr = w >> 1, wc = w & 1;
  int row0 = tm * 128;
  f32x4 acc[4][4] = {};
  gemm_k_dbuf64<8>(A + (size_t)row0 * D_, D_, BT + (size_t)(tn * 128) * D_, D_,
                   t, wr, wc, l15, g, As, Bs, acc);
  int sel = tn >> 2, col0 = (tn & 3) * 128;
  if (sel < 2) {
    uint16_t* dst = sel == 0 ? Qb : Kb;
    const float* bias = sel == 0 ? bq : bk;
    float scl = sel == 0 ? 0.125f : 1.0f;
#pragma unroll
    for (int m = 0; m < 4; ++m) {
      int r = row0 + wr * 64 + m * 16 + g * 4;
#pragma unroll
      for (int n = 0; n < 4; ++n) {
        int c = col0 + wc * 64 + n * 16 + l15;
#pragma unroll
        for (int j = 0; j < 4; ++j)
          dst[(size_t)(r + j) * D_ + c] = f2bf((acc[m][n][j] + bias[c]) * scl);
      }
    }
  } else {
    // V: store transposed [b][h][d][s] for direct attn staging
#pragma unroll
    for (int m = 0; m < 4; ++m) {
      int tb = row0 + wr * 64 + m * 16 + g * 4;
      int b = tb >> 11, s = tb & 2047;
#pragma unroll
      for (int n = 0; n < 4; ++n) {
        int c = col0 + wc * 64 + n * 16 + l15;
        int hh = c >> 6, d = c & 63;
        u16x4 pack;
#pragma unroll
        for (int j = 0; j < 4; ++j) pack[j] = f2bf(acc[m][n][j] + bv[c]);
        *(u16x4*)(VT + ((size_t)((b * H_ + hh) * HD_ + d) * S_ + s)) = pack;
      }
    }
  }
}

// ---------------- WO GEMM + bias + residual -> out (f32) + x2 (bf16) --------
__global__ __launch_bounds__(256) void gemm_wo_kernel(
    const uint16_t* __restrict__ A, const uint16_t* __restrict__ BT,
    const float* __restrict__ bo, const float* __restrict__ res,
    float* __restrict__ out, uint16_t* __restrict__ x2bf) {
  __shared__ __align__(16) uint16_t As[2][8192], Bs[2][8192];
  int tm = blockIdx.x, tn = blockIdx.y;
  int t = threadIdx.x;
  int w = t >> 6, l = t & 63, l15 = l & 15, g = l >> 4;
  int wr = w >> 1, wc = w & 1;
  int row0 = tm * 128;
  f32x4 acc[4][4] = {};
  gemm_k_dbuf64<8>(A + (size_t)row0 * D_, D_, BT + (size_t)(tn * 128) * D_, D_,
                   t, wr, wc, l15, g, As, Bs, acc);
#pragma unroll
  for (int m = 0; m < 4; ++m) {
    int r = row0 + wr * 64 + m * 16 + g * 4;
#pragma unroll
    for (int n = 0; n < 4; ++n) {
      int c = tn * 128 + wc * 64 + n * 16 + l15;
#pragma unroll
      for (int j = 0; j < 4; ++j) {
        float v = acc[m][n][j] + bo[c] + res[(size_t)(r + j) * D_ + c];
        out[(size_t)(r + j) * D_ + c] = v;
        x2bf[(size_t)(r + j) * D_ + c] = f2bf(v);
      }
    }
  }
}

// ---------------- MFMA flash attention, swapped-QK softmax ------------------
__global__ __launch_bounds__(256) void attn_mfma_kernel(
    const uint16_t* __restrict__ Qbf, const uint16_t* __restrict__ Kbf,
    const uint16_t* __restrict__ VT, uint16_t* __restrict__ obf) {
  __shared__ __align__(16) uint16_t Ks[2][4096];   // [64 key][64 d] swizzled
  __shared__ __align__(16) uint16_t Vt[2][4096];   // [64 d][64 key] swizzled
  __shared__ __align__(16) uint16_t Plds[4096];    // per-wave [16 q][64 k] swz
  int qt = blockIdx.x, h = blockIdx.y, b = blockIdx.z;
  int t = threadIdx.x, w = t >> 6, l = t & 63;
  int l15 = l & 15, g = l >> 4;
  int qbase = b * S_ + qt * 64;
  bf16x8 qb_[2];
  {
    const uint16_t* qp = Qbf + (size_t)(qbase + w * 16 + l15) * D_ + h * HD_;
#pragma unroll
    for (int ks = 0; ks < 2; ++ks)
      qb_[ks] = *(const bf16x8*)(qp + ks * 32 + g * 8);
  }
  const uint16_t* Kbase = Kbf + (size_t)(b * S_) * D_ + h * HD_;
  const uint16_t* Vbase = VT + (size_t)((b * H_ + h) * HD_) * S_;
  int r0 = t >> 3, slot = t & 7, r1 = r0 + 32;
  int sb0 = (slot * 16) ^ ((r0 & 7) << 4);
  int sb1 = (slot * 16) ^ ((r1 & 7) << 4);
  int ldst = (t & ~63) * 16;

  auto stage_kv = [&](int kt, int buf) {
    const uint16_t* Kp = Kbase + (size_t)(kt * 64) * D_;
    const uint16_t* Vp = Vbase + kt * 64;
    GLOAD_LDS16((const char*)(Kp + (size_t)r0 * D_) + sb0, (char*)Ks[buf] + ldst);
    GLOAD_LDS16((const char*)(Kp + (size_t)r1 * D_) + sb1, (char*)Ks[buf] + 4096 + ldst);
    GLOAD_LDS16((const char*)(Vp + (size_t)r0 * S_) + sb0, (char*)Vt[buf] + ldst);
    GLOAD_LDS16((const char*)(Vp + (size_t)r1 * S_) + sb1, (char*)Vt[buf] + 4096 + ldst);
  };

  f32x4 acc_o[4] = {};
  float m_run = -INFINITY, l_run = 0.f;  // state for q = l15 of this wave
  char* Pw = (char*)Plds + w * 2048;

  stage_kv(0, 0);
  int cur = 0;
  for (int kt = 0; kt < S_ / 64; ++kt) {
    if (kt + 1 < S_ / 64) {
      stage_kv(kt + 1, cur ^ 1);
      VMCNT(4);
    } else {
      VMCNT(0);
    }
    BARRIER; MEMBAR;
    const char* KsC = (const char*)Ks[cur];
    const char* VtC = (const char*)Vt[cur];
    f32x4 accs[4] = {};
#pragma unroll
    for (int ks = 0; ks < 2; ++ks) {
#pragma unroll
      for (int m = 0; m < 4; ++m) {
        int row = m * 16 + l15;
        bf16x8 kf = *(const bf16x8*)(KsC +
                        (row * 128 + ((ks * 64 + g * 16) ^ ((row & 7) << 4))));
        accs[m] = __builtin_amdgcn_mfma_f32_16x16x32_bf16(kf, qb_[ks], accs[m], 0, 0, 0);
      }
    }
    float mx = accs[0][0];
#pragma unroll
    for (int m = 0; m < 4; ++m)
#pragma unroll
      for (int j = 0; j < 4; ++j) mx = fmaxf(mx, accs[m][j]);
    mx = fmaxf(mx, __shfl_xor(mx, 16));
    mx = fmaxf(mx, __shfl_xor(mx, 32));
    float mnew = fmaxf(m_run, mx);
    float corr = __expf(m_run - mnew);
    m_run = mnew;
    float sum = 0.f;
#pragma unroll
    for (int m = 0; m < 4; ++m) {
      float p0 = __expf(accs[m][0] - mnew);
      float p1 = __expf(accs[m][1] - mnew);
      float p2 = __expf(accs[m][2] - mnew);
      float p3 = __expf(accs[m][3] - mnew);
      sum += (p0 + p1) + (p2 + p3);
      uint2 pk;
      pk.x = (uint32_t)f2bf(p0) | ((uint32_t)f2bf(p1) << 16);
      pk.y = (uint32_t)f2bf(p2) | ((uint32_t)f2bf(p3) << 16);
      *(uint2*)(Pw + (l15 * 128 + ((m * 32 + g * 8) ^ ((l15 & 7) << 4)))) = pk;
    }
    sum += __shfl_xor(sum, 16);
    sum += __shfl_xor(sum, 32);
    l_run = l_run * corr + sum;
    float cj[4];
#pragma unroll
    for (int j = 0; j < 4; ++j) cj[j] = __shfl(corr, g * 4 + j);
#pragma unroll
    for (int n = 0; n < 4; ++n)
#pragma unroll
      for (int j = 0; j < 4; ++j) acc_o[n][j] *= cj[j];
#pragma unroll
    for (int ks = 0; ks < 2; ++ks) {
      bf16x8 pa = *(const bf16x8*)(Pw +
                      (l15 * 128 + ((ks * 64 + g * 16) ^ ((l15 & 7) << 4))));
#pragma unroll
      for (int n = 0; n < 4; ++n) {
        int d = n * 16 + l15;
        bf16x8 vb = *(const bf16x8*)(VtC +
                        (d * 128 + ((ks * 64 + g * 16) ^ ((d & 7) << 4))));
        acc_o[n] = __builtin_amdgcn_mfma_f32_16x16x32_bf16(pa, vb, acc_o[n], 0, 0, 0);
      }
    }
    MEMBAR; BARRIER;
    cur ^= 1;
  }
#pragma unroll
  for (int j = 0; j < 4; ++j) {
    float lr = __shfl(l_run, g * 4 + j);
    float inv = 1.f / lr;
    uint16_t* op = obf + (size_t)(qbase + w * 16 + g * 4 + j) * D_ + h * HD_;
#pragma unroll
    for (int n = 0; n < 4; ++n)
      op[n * 16 + l15] = f2bf(acc_o[n][j] * inv);
  }
}

// ---------------- MoE bucketing: group tokens, pad to 128 -------------------
__global__ __launch_bounds__(1024) void bucket_kernel(
    const int* __restrict__ gid, int* __restrict__ list, int* __restrict__ poff) {
  __shared__ int cnt[G_], cur[G_];
  int t = threadIdx.x;
  if (t < G_) cnt[t] = 0;
  __syncthreads();
  for (int i = t; i < N_; i += 1024) atomicAdd(&cnt[gid[i]], 1);
  __syncthreads();
  if (t == 0) {
    int off = 0;
    for (int g = 0; g < G_; ++g) {
      poff[g] = off;
      cur[g] = off;
      off += (cnt[g] + 127) & ~127;
    }
    poff[G_] = off;
  }
  __syncthreads();
  for (int i = t; i < PADCAP_; i += 1024) list[i] = N_;
  __syncthreads();
  for (int i = t; i < N_; i += 1024) {
    int p = atomicAdd(&cur[gid[i]], 1);
    list[p] = i;
  }
}

// ---------------- MoE FF1 (gathered A), swizzled dbuf, experts via grid.z ---
__global__ __launch_bounds__(256) void ff1_mfma_kernel(
    const uint16_t* __restrict__ X, const uint16_t* __restrict__ w1T,
    const float* __restrict__ b1, const int* __restrict__ list,
    const int* __restrict__ poff, uint16_t* __restrict__ hid) {
  __shared__ __align__(16) uint16_t As[2][8192], Bs[2][8192];
  int tm = blockIdx.x, tn = blockIdx.y, e = blockIdx.z;
  int slot0 = tm * 128;
  if (slot0 >= poff[G_]) return;
  int g_ = 0;
#pragma unroll
  for (int gg = 1; gg < G_; ++gg) g_ += (slot0 >= poff[gg]);
  int t = threadIdx.x;
  int w = t >> 6, l = t & 63, l15 = l & 15, g = l >> 4;
  int wr = w >> 1, wc = w & 1;
  int r8 = t >> 3, clog = (t & 7) ^ (r8 & 7);
  int ubase = (t & ~63) * 8;
  int tok[4];
#pragma unroll
  for (int pi = 0; pi < 4; ++pi) tok[pi] = list[slot0 + pi * 32 + r8];
  const uint16_t* Bb = w1T + ((size_t)(g_ * E_ + e) * FF_ + tn * 128) * D_;
  f32x4 acc[4][4] = {};
  auto stage = [&](int k0, int buf) {
#pragma unroll
    for (int pi = 0; pi < 4; ++pi) {
      GLOAD_LDS16(X + (size_t)tok[pi] * D_ + k0 + clog * 8, As[buf] + pi * 2048 + ubase);
      GLOAD_LDS16(Bb + (size_t)(pi * 32 + r8) * D_ + k0 + clog * 8,
                  Bs[buf] + pi * 2048 + ubase);
    }
  };
  stage(0, 0);
  int cur = 0;
  for (int ki = 0; ki < 8; ++ki) {
    if (ki + 1 < 8) {
      stage((ki + 1) * 64, cur ^ 1);
      VMCNT(8);
    } else {
      VMCNT(0);
    }
    BARRIER; MEMBAR;
    kstep_swz((const char*)As[cur], (const char*)Bs[cur], wr, wc, l15, g, acc);
    MEMBAR; BARRIER;
    cur ^= 1;
  }
  const float* bias = b1 + (size_t)(g_ * E_ + e) * FF_;
  uint16_t* hidE = hid + (size_t)e * PADCAP_ * FF_;
#pragma unroll
  for (int m = 0; m < 4; ++m) {
    int r = slot0 + wr * 64 + m * 16 + g * 4;
#pragma unroll
    for (int n = 0; n < 4; ++n) {
      int c = tn * 128 + wc * 64 + n * 16 + l15;
#pragma unroll
      for (int j = 0; j < 4; ++j)
        hidE[(size_t)(r + j) * FF_ + c] = f2bf(gelu_f(acc[m][n][j] + bias[c]));
    }
  }
}

// ---------------- MoE FF2: per-expert blocks, atomic scatter-add ------------
__global__ __launch_bounds__(256) void ff2_mfma_kernel(
    const uint16_t* __restrict__ hid, const uint16_t* __restrict__ w2T,
    const float* __restrict__ b2, const int* __restrict__ list,
    const int* __restrict__ poff, float* __restrict__ out) {
  __shared__ __align__(16) uint16_t As[2][8192], Bs[2][8192];
  int tm = blockIdx.x, tn = blockIdx.y, e = blockIdx.z;
  int slot0 = tm * 128;
  if (slot0 >= poff[G_]) return;
  int g_ = 0;
#pragma unroll
  for (int gg = 1; gg < G_; ++gg) g_ += (slot0 >= poff[gg]);
  int t = threadIdx.x;
  int w = t >> 6, l = t & 63, l15 = l & 15, g = l >> 4;
  int wr = w >> 1, wc = w & 1;
  f32x4 acc[4][4] = {};
  const uint16_t* Ab = hid + ((size_t)e * PADCAP_ + slot0) * FF_;
  const uint16_t* Bb = w2T + (size_t)(g_ * E_ + e) * D_ * FF_ + (size_t)(tn * 128) * FF_;
  gemm_k_dbuf64<32>(Ab, FF_, Bb, FF_, t, wr, wc, l15, g, As, Bs, acc);
  const float* be = b2 + (size_t)(g_ * E_ + e) * D_;
#pragma unroll
  for (int m = 0; m < 4; ++m) {
    int rbase = slot0 + wr * 64 + m * 16 + g * 4;
#pragma unroll
    for (int j = 0; j < 4; ++j) {
      int tok = list[rbase + j];
      if (tok >= N_) continue;
#pragma unroll
      for (int n = 0; n < 4; ++n) {
        int c = tn * 128 + wc * 64 + n * 16 + l15;
        atomicAdd(&out[(size_t)tok * D_ + c], 0.5f * (acc[m][n][j] + be[c]));
      }
    }
  }
}

}  // namespace

extern "C" void kernel_launch(void* const* d_in, const int* in_sizes, int n_in,
                              void* d_out, int out_size, void* d_ws, size_t ws_size,
                              hipStream_t stream) {
  const float* x = (const float*)d_in[0];
  const int* gid = (const int*)d_in[1];
  const float* ln1s = (const float*)d_in[2];
  const float* ln1b = (const float*)d_in[3];
  const float* ck = (const float*)d_in[4];
  const float* cb = (const float*)d_in[5];
  const float* ln2s = (const float*)d_in[6];
  const float* ln2b = (const float*)d_in[7];
  const float* wq = (const float*)d_in[8];
  const float* bq = (const float*)d_in[9];
  const float* wk = (const float*)d_in[10];
  const float* bk = (const float*)d_in[11];
  const float* wv = (const float*)d_in[12];
  const float* bv = (const float*)d_in[13];
  const float* wo = (const float*)d_in[14];
  const float* bo = (const float*)d_in[15];
  const float* w1 = (const float*)d_in[16];
  const float* b1 = (const float*)d_in[17];
  const float* w2 = (const float*)d_in[18];
  const float* b2 = (const float*)d_in[19];
  float* out = (float*)d_out;

  char* ws = (char*)d_ws;
  // Region A (38 MiB), time-multiplexed:
  //  conv:  P[8] bf16 partials (32 MiB)
  //  attn:  ln2bf(4) | Qbf(4) | Kbf(4) | VT(4) | obf(4)   [bf16]
  //  moe:   hidbf (36 MiB)
  char* A = ws;
  uint16_t* P = (uint16_t*)A;
  uint16_t* ln2bf = (uint16_t*)A;
  uint16_t* Qbf = (uint16_t*)(A + (4ull << 20));
  uint16_t* Kbf = (uint16_t*)(A + (8ull << 20));
  uint16_t* VT = (uint16_t*)(A + (12ull << 20));
  uint16_t* obf = (uint16_t*)(A + (16ull << 20));
  uint16_t* hidbf = (uint16_t*)A;

  float* x1 = (float*)(ws + (38ull << 20));
  uint16_t* Hpad = (uint16_t*)(ws + (46ull << 20));
  uint16_t* ckT = (uint16_t*)(ws + (51ull << 20));
  uint16_t* wqkvT = (uint16_t*)(ws + (67ull << 20));
  uint16_t* woT = (uint16_t*)(ws + (69ull << 20));
  uint16_t* w1T = (uint16_t*)(ws + (70ull << 20));
  uint16_t* w2T = (uint16_t*)(ws + (86ull << 20));
  uint16_t* x2bf = (uint16_t*)(ws + (102ull << 20));
  int* list = (int*)(ws + (107ull << 20));
  int* poff = list + PADCAP_;

  prep_kernel<<<25405, 256, 0, stream>>>(ck, wq, wk, wv, wo, w1, w2,
                                         ckT, wqkvT, woT, w1T, w2T, Hpad, x2bf);
  bucket_kernel<<<1, 1024, 0, stream>>>(gid, list, poff);

  // conv sublayer
  ln_bf16_kernel<<<N_, 256, 0, stream>>>(x, Hpad, ln1s, ln1b, 1);
  conv_mfma_kernel<<<256, 512, 0, stream>>>(Hpad, ckT, P);
  conv_epi_kernel<<<1024, 256, 0, stream>>>(P, cb, x, x1);

  // attention sublayer
  ln_bf16_kernel<<<N_, 256, 0, stream>>>(x1, ln2bf, ln2s, ln2b, 0);
  gemm_qkv_kernel<<<dim3(32, 12), 256, 0, stream>>>(ln2bf, wqkvT, bq, bk, bv, Qbf, Kbf, VT);
  attn_mfma_kernel<<<dim3(S_ / 64, H_, B_), 256, 0, stream>>>(Qbf, Kbf, VT, obf);
  gemm_wo_kernel<<<dim3(32, 4), 256, 0, stream>>>(obf, woT, bo, x1, out, x2bf);

  // MoE sublayer
  ff1_mfma_kernel<<<dim3(36, 16, 2), 256, 0, stream>>>(x2bf, w1T, b1, list, poff, hidbf);
  ff2_mfma_kernel<<<dim3(36, 4, 2), 256, 0, stream>>>(hidbf, w2T, b2, list, poff, out);
}